// Round 5
// baseline (169.223 us; speedup 1.0000x reference)
//
#include <hip/hip_runtime.h>
#include <hip/hip_bf16.h>
#include <math.h>

typedef __attribute__((ext_vector_type(8))) short short8;
typedef __attribute__((ext_vector_type(4))) short short4v;
typedef __attribute__((ext_vector_type(4))) float float4v;
typedef __attribute__((ext_vector_type(2))) unsigned int uint2v;
typedef unsigned short ushort_t;

constexpr int NPTS = 32768;  // B*N
constexpr int NN   = 16384;  // points per batch
constexpr int KK   = 32;     // neighbors
constexpr int CC   = 128;    // channels
constexpr int GRP  = 16;     // points per block -> grid 2048
constexpr int SR   = 136;    // res LDS row stride (shorts)
constexpr int SG2  = 24;     // fallback geo stride
#define LN_EPS 1e-5f
#define MFMA   __builtin_amdgcn_mfma_f32_16x16x32_bf16
#define GLL(src, dst, sz) __builtin_amdgcn_global_load_lds( \
    (const __attribute__((address_space(1))) void*)(src),   \
    (__attribute__((address_space(3))) void*)(dst), sz, 0, 0)

// ---- new-path workspace layout ----
constexpr size_t WS_FW  = 0;                       // FW bf16: 32768*128*2 = 8388608
constexpr size_t WS_WO  = (size_t)NPTS * CC * 2;   // w_out swizzled: 32768 B
constexpr size_t WS_BE  = WS_WO + 32768;           // beff: 512 B
constexpr size_t WS_W4  = WS_BE + 512;             // W4 packed [col][8]: 2048 B
constexpr size_t WS_WC  = WS_W4 + 2048;            // Wc: 3*128 f32 = 1536 B
constexpr size_t WS_WPF = WS_WC + 1536;            // w_gcm frag-packed: 16*128*8*2 = 32768 B
constexpr size_t WS_NEED = WS_WPF + 32768;         // 8458240 < old 8467968 -> known available
// ---- fallback workspace layout (old scheme, small) ----
constexpr size_t FB_WP = 0, FB_WO = 40960, FB_BE = 73728, FB_PG = 74240;

__device__ __forceinline__ short f2bs(float x) {
    return (short)__builtin_bit_cast(unsigned short, __float2bfloat16(x));
}
__device__ __forceinline__ float bs2f(ushort_t u) {
    return __uint_as_float(((unsigned)u) << 16);
}

// ================= prep A: weight packs (3 blocks) =================
// blk 0: wsWpF = w_gcm frag-packed (g,n,j) -> w_gcm[(g*8+j)][n]
// blk 1: wsWo  = w_out frag-packed
// blk 2: PG = w_pos@w_gcm -> beff, W4, Wc
__global__ __launch_bounds__(256) void prep_w(
    const float* __restrict__ w_gcm, const float* __restrict__ w_out,
    const float* __restrict__ w_pos, const float* __restrict__ b_pos,
    const float* __restrict__ b_gcm,
    short* __restrict__ wsWpF, short* __restrict__ wsWo,
    float* __restrict__ wsBeff, short* __restrict__ wsW4, float* __restrict__ wsWc)
{
    const int t = threadIdx.x, blk = blockIdx.x;
    __shared__ float sPG[10 * 128];
    if (blk == 0) {
        #pragma unroll 4
        for (int e = t; e < 16 * 128 * 8; e += 256) {
            const int j = e & 7, n = (e >> 3) & 127, g = e >> 10;
            wsWpF[e] = f2bs(w_gcm[(g * 8 + j) * 128 + n]);
        }
    } else if (blk == 1) {
        #pragma unroll 4
        for (int e = t; e < 128 * 128; e += 256) {
            const int j = e & 7, n = (e >> 3) & 127, g = e >> 10;
            wsWo[e] = f2bs(w_out[(g * 8 + j) * 128 + n]);
        }
    } else {
        if (t < 128) {
            const int c = t;
            for (int g = 0; g < 10; ++g) {
                float s = 0.f;
                for (int r = 0; r < 128; ++r) s += w_pos[g * 128 + r] * w_gcm[r * 128 + c];
                sPG[g * 128 + c] = s;
            }
            float sb = b_gcm[c];
            for (int r = 0; r < 128; ++r) sb += b_pos[r] * w_gcm[r * 128 + c];
            wsBeff[c] = sb;
        }
        __syncthreads();
        if (t < 128) {
            const int c = t;
            short8 v = (short8)0;
            v[0] = f2bs(sPG[3 * 128 + c] + sPG[6 * 128 + c]);
            v[1] = f2bs(sPG[4 * 128 + c] + sPG[7 * 128 + c]);
            v[2] = f2bs(sPG[5 * 128 + c] + sPG[8 * 128 + c]);
            v[3] = f2bs(sPG[9 * 128 + c]);
            *(short8*)&wsW4[c * 8] = v;
            wsWc[0 * 128 + c] = sPG[0 * 128 + c] - sPG[6 * 128 + c];
            wsWc[1 * 128 + c] = sPG[1 * 128 + c] - sPG[7 * 128 + c];
            wsWc[2 * 128 + c] = sPG[2 * 128 + c] - sPG[8 * 128 + c];
        }
    }
}

// ================= prep B: FW = features @ w_gcm (bf16), 16 rows/block =================
__global__ __launch_bounds__(256) void prep_fw(
    const float* __restrict__ features, const short* __restrict__ wsWpF,
    ushort_t* __restrict__ wsFW)
{
    const int t = threadIdx.x, blk = blockIdx.x;
    __shared__ short sF[16 * SR];
    const int g0 = blk * GRP;
    {   // stage features tile (f32 -> bf16), coalesced
        const int row = t >> 4, c8 = (t & 15) * 8;
        const float* fp = features + (size_t)(g0 + row) * CC + c8;
        const float4 a = *(const float4*)fp;
        const float4 b = *(const float4*)(fp + 4);
        short8 v;
        v[0]=f2bs(a.x); v[1]=f2bs(a.y); v[2]=f2bs(a.z); v[3]=f2bs(a.w);
        v[4]=f2bs(b.x); v[5]=f2bs(b.y); v[6]=f2bs(b.z); v[7]=f2bs(b.w);
        *(short8*)&sF[row * SR + c8] = v;
    }
    const int wv = t >> 6, lane = t & 63, quad = (lane >> 4) & 3, m = lane & 15;
    const int col0 = wv * 32 + m;
    short8 bf[4][2];
    #pragma unroll
    for (int ks = 0; ks < 4; ++ks) {
        bf[ks][0] = *((const short8*)wsWpF + ((ks * 4 + quad) * 128 + col0));
        bf[ks][1] = *((const short8*)wsWpF + ((ks * 4 + quad) * 128 + col0 + 16));
    }
    __syncthreads();
    float4v acc[2] = {};
    #pragma unroll
    for (int ks = 0; ks < 4; ++ks) {
        const short8 a = *(const short8*)(sF + m * SR + ks * 32 + quad * 8);
        acc[0] = MFMA(a, bf[ks][0], acc[0], 0, 0, 0);
        acc[1] = MFMA(a, bf[ks][1], acc[1], 0, 0, 0);
    }
    #pragma unroll
    for (int r = 0; r < 4; ++r) {
        const int R = quad * 4 + r;
        wsFW[(size_t)(g0 + R) * CC + col0]      = (ushort_t)f2bs(acc[0][r]);
        wsFW[(size_t)(g0 + R) * CC + col0 + 16] = (ushort_t)f2bs(acc[1][r]);
    }
}

// ================= main kernel: barrier-free FW-gather + rank-4 geo MFMA =================
// tr-read semantics (derived from m156/m162): lane fetches its own 8B chunk at
// addr = base + lane*8; out(l,j) = chunk(j*4 + ((l&15)>>2))[(l&15)&3] within each
// 16-lane group. DMA source roles (rbL/jL/hL) lay FW out so that
// out(q,m,r) = FW[k=q*4+r][wave-ch m] at region offsets {0,512,1024,1536}.
__global__ __launch_bounds__(256, 3) void bridge_fw(
    const float* __restrict__ points, const float* __restrict__ features,
    const int*   __restrict__ gidx,
    const short* __restrict__ wsWo, const float* __restrict__ wsBeff,
    const short* __restrict__ wsW4, const float* __restrict__ wsWc,
    const ushort_t* __restrict__ wsFW,
    const float* __restrict__ b_out, const float* __restrict__ ln_g,
    const float* __restrict__ ln_b, float* __restrict__ out)
{
    __shared__ short sA[4][3][1024];      // [wave][buf] gathered FW tiles (24 KB)
    __shared__ float sGxyz[GRP * KK * 3]; // all neighbor xyz (6 KB)
    __shared__ short sRes[GRP * SR];
    __shared__ short sResF[GRP * CC];
    __shared__ int   sIdx[GRP * KK];
    __shared__ float sCtr[GRP * 3];
    __shared__ float sPS[4][GRP], sPQ[4][GRP];

    const int t = threadIdx.x, wv = t >> 6, lane = t & 63;
    const int q = (lane >> 4) & 3, m = lane & 15;
    const int g0 = blockIdx.x * GRP;
    const int nbase = (g0 >= NN) ? NN : 0;
    const int colA = wv * 32 + m;
    const int rbL = lane >> 3, jL = (lane & 7) >> 1, hL = lane & 1;  // DMA lane roles

    // ---- prologue staging (plain loads; drained by the one __syncthreads) ----
    {
        const int gA = gidx[(size_t)g0 * KK + t];
        const int gB = gidx[(size_t)g0 * KK + t + 256];
        sIdx[t] = gA; sIdx[t + 256] = gB;
        const float* pA = points + (size_t)(nbase + gA) * 3;
        const float* pB = points + (size_t)(nbase + gB) * 3;
        sGxyz[t * 3 + 0] = pA[0]; sGxyz[t * 3 + 1] = pA[1]; sGxyz[t * 3 + 2] = pA[2];
        sGxyz[(t + 256) * 3 + 0] = pB[0];
        sGxyz[(t + 256) * 3 + 1] = pB[1];
        sGxyz[(t + 256) * 3 + 2] = pB[2];
    }
    if (t < GRP * 3) sCtr[t] = points[(size_t)g0 * 3 + t];
    {   // residual features f32 -> bf16
        const int row = t >> 4, c8 = (t & 15) * 8;
        const float* fp = features + (size_t)(g0 + row) * CC + c8;
        const float4 a = *(const float4*)fp;
        const float4 b = *(const float4*)(fp + 4);
        short8 v;
        v[0]=f2bs(a.x); v[1]=f2bs(a.y); v[2]=f2bs(a.z); v[3]=f2bs(a.w);
        v[4]=f2bs(b.x); v[5]=f2bs(b.y); v[6]=f2bs(b.z); v[7]=f2bs(b.w);
        *(short8*)&sResF[row * CC + c8] = v;
    }

    const float beffv[2] = { wsBeff[colA], wsBeff[colA + 16] };
    float wc[6];
    #pragma unroll
    for (int i = 0; i < 3; ++i) { wc[i] = wsWc[i * 128 + colA]; wc[3 + i] = wsWc[i * 128 + colA + 16]; }
    short8 w4f[2];
    #pragma unroll
    for (int n = 0; n < 2; ++n) {
        const short8 w = *((const short8*)wsW4 + (colA + n * 16));
        w4f[n] = (q == 0) ? w : (short8)0;
    }
    // FIX vs R4: per-lane tr address must be base + lane*8 (was m*2 -> garbage)
    const unsigned trBase = (unsigned)(size_t)(__attribute__((address_space(3))) short*)&sA[wv][0][0]
                          + (unsigned)(lane * 8);

    __syncthreads();   // drains ALL prologue vmem; the only block-wide barrier before the tail

    auto issue_fw = [&](int p, int buf) {
        // lane (rb=lane>>3, j2=(lane&7)>>1, h=lane&1) fetches row k, channels [h*8,h*8+8)
        // GLL0 -> regions A,B (ch 0..15); GLL1 (+16ch) -> regions C,D at byte 1024.
        const int kw = nbase + sIdx[p * KK + rbL * 4 + jL];
        const ushort_t* s0 = wsFW + (size_t)kw * CC + wv * 32 + hL * 8;
        GLL(s0,      &sA[wv][buf][0],   16);
        GLL(s0 + 16, &sA[wv][buf][512], 16);
    };

    issue_fw(0, 0);
    issue_fw(1, 1);

    #pragma unroll
    for (int p = 0; p < GRP; ++p) {
        const int buf = p % 3;
        if (p + 2 < GRP) issue_fw(p + 2, (p + 2) % 3);
        // in-loop vmem stream is ONLY the GLLs -> counts exact
        if (p + 2 < GRP)      asm volatile("s_waitcnt vmcnt(4)" ::: "memory");
        else if (p + 1 < GRP) asm volatile("s_waitcnt vmcnt(2)" ::: "memory");
        else                  asm volatile("s_waitcnt vmcnt(0)" ::: "memory");
        __builtin_amdgcn_sched_barrier(0);

        // C fragments: FW[k=q*4+r][colA(+16)] via hardware transpose read
        uint2v t00, t10, t01, t11;
        const unsigned trA = trBase + (unsigned)(buf * 2048);
        asm volatile("ds_read_b64_tr_b16 %0, %1 offset:0"    : "=&v"(t00) : "v"(trA));
        asm volatile("ds_read_b64_tr_b16 %0, %1 offset:512"  : "=&v"(t10) : "v"(trA));
        asm volatile("ds_read_b64_tr_b16 %0, %1 offset:1024" : "=&v"(t01) : "v"(trA));
        asm volatile("ds_read_b64_tr_b16 %0, %1 offset:1536" : "=&v"(t11) : "v"(trA));

        const float pcx = sCtr[p * 3], pcy = sCtr[p * 3 + 1], pcz = sCtr[p * 3 + 2];
        short8 ga0 = (short8)0, ga1 = (short8)0;
        if (q == 0) {   // folded geo A-frag: k-dims {gx, gy, gz, dist}
            const int i0 = (p * KK + m) * 3, i1 = i0 + 48;
            const float ax = sGxyz[i0], ay = sGxyz[i0 + 1], az = sGxyz[i0 + 2];
            const float bx = sGxyz[i1], by = sGxyz[i1 + 1], bz = sGxyz[i1 + 2];
            const float d0x = ax - pcx, d0y = ay - pcy, d0z = az - pcz;
            const float d1x = bx - pcx, d1y = by - pcy, d1z = bz - pcz;
            const float s0 = sqrtf(d0x * d0x + d0y * d0y + d0z * d0z);
            const float s1 = sqrtf(d1x * d1x + d1y * d1y + d1z * d1z);
            ga0[0]=f2bs(ax); ga0[1]=f2bs(ay); ga0[2]=f2bs(az); ga0[3]=f2bs(s0);
            ga1[0]=f2bs(bx); ga1[1]=f2bs(by); ga1[2]=f2bs(bz); ga1[3]=f2bs(s1);
        }

        asm volatile("s_waitcnt lgkmcnt(0)" ::: "memory");   // tr-reads complete
        __builtin_amdgcn_sched_barrier(0);                   // rule #18: pin consumers below

        // unpack gathered FW (bf16 -> f32) as MFMA C-input
        float4v c00, c10, c01, c11;
        c00[0]=__uint_as_float(t00[0] << 16); c00[1]=__uint_as_float(t00[0] & 0xffff0000u);
        c00[2]=__uint_as_float(t00[1] << 16); c00[3]=__uint_as_float(t00[1] & 0xffff0000u);
        c10[0]=__uint_as_float(t10[0] << 16); c10[1]=__uint_as_float(t10[0] & 0xffff0000u);
        c10[2]=__uint_as_float(t10[1] << 16); c10[3]=__uint_as_float(t10[1] & 0xffff0000u);
        c01[0]=__uint_as_float(t01[0] << 16); c01[1]=__uint_as_float(t01[0] & 0xffff0000u);
        c01[2]=__uint_as_float(t01[1] << 16); c01[3]=__uint_as_float(t01[1] & 0xffff0000u);
        c11[0]=__uint_as_float(t11[0] << 16); c11[1]=__uint_as_float(t11[0] & 0xffff0000u);
        c11[2]=__uint_as_float(t11[1] << 16); c11[3]=__uint_as_float(t11[1] & 0xffff0000u);

        c00 = MFMA(ga0, w4f[0], c00, 0, 0, 0);
        c01 = MFMA(ga0, w4f[1], c01, 0, 0, 0);
        c10 = MFMA(ga1, w4f[0], c10, 0, 0, 0);
        c11 = MFMA(ga1, w4f[1], c11, 0, 0, 0);

        const float cb0 = pcx * wc[0] + pcy * wc[1] + pcz * wc[2];
        const float cb1 = pcx * wc[3] + pcy * wc[4] + pcz * wc[5];

        float v0 = fmaxf(fmaxf(fmaxf(c00[0],c00[1]), fmaxf(c00[2],c00[3])),
                         fmaxf(fmaxf(c10[0],c10[1]), fmaxf(c10[2],c10[3])));
        float v1 = fmaxf(fmaxf(fmaxf(c01[0],c01[1]), fmaxf(c01[2],c01[3])),
                         fmaxf(fmaxf(c11[0],c11[1]), fmaxf(c11[2],c11[3])));
        v0 = fmaxf(v0, __shfl_xor(v0, 16)); v0 = fmaxf(v0, __shfl_xor(v0, 32));
        v1 = fmaxf(v1, __shfl_xor(v1, 16)); v1 = fmaxf(v1, __shfl_xor(v1, 32));
        v0 = fmaxf(v0 + beffv[0] + cb0, 0.f);
        v1 = fmaxf(v1 + beffv[1] + cb1, 0.f);
        if (q == 0) {
            sRes[p * SR + colA]      = f2bs(v0 + bs2f((ushort_t)sResF[p * CC + colA]));
            sRes[p * SR + colA + 16] = f2bs(v1 + bs2f((ushort_t)sResF[p * CC + colA + 16]));
        }
    }

    __syncthreads();

    // ---- out projection: res(16x128) @ w_out(128x128) + LN + relu ----
    short8 bWo[4][2];
    #pragma unroll
    for (int ks = 0; ks < 4; ++ks)
        #pragma unroll
        for (int ntl = 0; ntl < 2; ++ntl)
            bWo[ks][ntl] = *((const short8*)wsWo + ((ks * 4 + q) * 128 + colA + ntl * 16));

    const short* rm = sRes + m * SR;
    float4v acc2[2] = {};
    #pragma unroll
    for (int ks = 0; ks < 4; ++ks) {
        const short8 a = *(const short8*)(rm + ks * 32 + q * 8);
        acc2[0] = MFMA(a, bWo[ks][0], acc2[0], 0, 0, 0);
        acc2[1] = MFMA(a, bWo[ks][1], acc2[1], 0, 0, 0);
    }

    const float boutv[2] = { b_out[colA], b_out[colA + 16] };
    const float lngv[2]  = { ln_g[colA], ln_g[colA + 16] };
    const float lnbv[2]  = { ln_b[colA], ln_b[colA + 16] };

    #pragma unroll
    for (int r = 0; r < 4; ++r) {
        const float o0 = acc2[0][r] + boutv[0];
        const float o1 = acc2[1][r] + boutv[1];
        float ss = o0 + o1, qq = o0 * o0 + o1 * o1;
        #pragma unroll
        for (int d = 1; d < 16; d <<= 1) { ss += __shfl_xor(ss, d); qq += __shfl_xor(qq, d); }
        if (m == 0) { sPS[wv][q * 4 + r] = ss; sPQ[wv][q * 4 + r] = qq; }
    }
    __syncthreads();

    #pragma unroll
    for (int r = 0; r < 4; ++r) {
        const int R = q * 4 + r;
        const float S = sPS[0][R] + sPS[1][R] + sPS[2][R] + sPS[3][R];
        const float Q = sPQ[0][R] + sPQ[1][R] + sPQ[2][R] + sPQ[3][R];
        const float mu  = S * (1.f / 128.f);
        const float var = fmaxf(Q * (1.f / 128.f) - mu * mu, 0.f);
        const float rstd = rsqrtf(var + LN_EPS);
        const float o0 = acc2[0][r] + boutv[0];
        const float o1 = acc2[1][r] + boutv[1];
        const size_t base = (size_t)(g0 + R) * CC;
        out[base + colA]      = fmaxf((o0 - mu) * rstd * lngv[0] + lnbv[0], 0.f);
        out[base + colA + 16] = fmaxf((o1 - mu) * rstd * lngv[1] + lnbv[1], 0.f);
    }
}

// ================= fallback path (small workspace; R2-verified structure, f32) =================
__global__ __launch_bounds__(128) void prep_fold_fb(
    const float* __restrict__ w_pos, const float* __restrict__ b_pos,
    const float* __restrict__ w_gcm, const float* __restrict__ b_gcm,
    float* __restrict__ wsPG, float* __restrict__ wsBeff)
{
    const int c = threadIdx.x, g = blockIdx.x;
    if (g < 10) {
        float s = 0.f;
        for (int r = 0; r < 128; ++r) s += w_pos[g * 128 + r] * w_gcm[r * 128 + c];
        wsPG[g * 128 + c] = s;
    } else {
        float s = b_gcm[c];
        for (int r = 0; r < 128; ++r) s += b_pos[r] * w_gcm[r * 128 + c];
        wsBeff[c] = s;
    }
}

__global__ __launch_bounds__(256) void prep_pack_fb(
    const float* __restrict__ w_gcm, const float* __restrict__ w_out,
    const float* __restrict__ wsPG, short* __restrict__ wsWp, short* __restrict__ wsWo)
{
    const int t = threadIdx.x, blk = blockIdx.x;
    if (blk == 0) {
        #pragma unroll 4
        for (int e = t; e < 16 * 128 * 8; e += 256) {
            const int j = e & 7, n = (e >> 3) & 127, g = e >> 10;
            wsWp[e] = f2bs(w_gcm[(g * 8 + j) * 128 + n]);
        }
    } else if (blk == 1) {
        #pragma unroll 4
        for (int e2 = t; e2 < 4 * 128 * 8; e2 += 256) {
            const int e = 16 * 128 * 8 + e2;
            const int j = e & 7, n = (e >> 3) & 127, g = e >> 10;
            const int k = g * 8 + j;
            wsWp[e] = (k < 138) ? f2bs(wsPG[(k - 128) * 128 + n]) : (short)0;
        }
    } else {
        #pragma unroll 4
        for (int e = t; e < 128 * 128; e += 256) {
            const int j = e & 7, n = (e >> 3) & 127, g = e >> 10;
            wsWo[e] = f2bs(w_out[(g * 8 + j) * 128 + n]);
        }
    }
}

__global__ __launch_bounds__(256, 3) void bridge_fb(
    const float* __restrict__ points, const float* __restrict__ features,
    const int*   __restrict__ gidx,
    const short* __restrict__ wsWp, const short* __restrict__ wsWo,
    const float* __restrict__ wsBeff,
    const float* __restrict__ b_out, const float* __restrict__ ln_g,
    const float* __restrict__ ln_b, float* __restrict__ out)
{
    __shared__ short sA[4][KK * CC];
    __shared__ short sG[3][KK * SG2];
    __shared__ short sRes[GRP * SR];
    __shared__ short sResF[GRP * CC];
    __shared__ int   sIdx[GRP * KK];
    __shared__ float sCtr[GRP * 3];
    __shared__ float sPS[4][GRP], sPQ[4][GRP];

    const int t = threadIdx.x, wv = t >> 6, lane = t & 63;
    const int quad = (lane >> 4) & 3, m = lane & 15;
    const int g0 = blockIdx.x * GRP;
    const int nbase = (g0 >= NN) ? NN : 0;
    const int col0 = wv * 32 + m;

    sIdx[t]       = gidx[(size_t)g0 * KK + t];
    sIdx[t + 256] = gidx[(size_t)g0 * KK + t + 256];
    if (t < GRP * 3) sCtr[t] = points[(size_t)g0 * 3 + t];
    {
        const float* fs = features + (size_t)g0 * CC + t * 8;
        short8 v;
        #pragma unroll
        for (int i = 0; i < 8; ++i) v[i] = f2bs(fs[i]);
        *(short8*)&sResF[t * 8] = v;
    }

    short8 bWp[5][2];
    #pragma unroll
    for (int ks = 0; ks < 5; ++ks)
        #pragma unroll
        for (int ntl = 0; ntl < 2; ++ntl)
            bWp[ks][ntl] = *((const short8*)wsWp + ((ks * 4 + quad) * 128 + col0 + ntl * 16));
    const float beffv[2] = { wsBeff[col0], wsBeff[col0 + 16] };

    __syncthreads();

    const int r0 = wv * 4 + (lane >> 4);
    const int pc = lane & 15;
    const int gc = pc ^ r0;

    float geoS[3][3];

    auto geo_load = [&](int qq) {
        if (lane < 8) {
            const int j = wv * 8 + lane;
            const int kng = nbase + sIdx[qq * KK + j];
            const float* pp = points + (size_t)kng * 3;
            const int s = qq % 3;
            geoS[s][0] = pp[0]; geoS[s][1] = pp[1]; geoS[s][2] = pp[2];
        }
    };
    auto stage = [&](int qq) {
        const int buf = qq & 3;
        const int kn0 = nbase + sIdx[qq * KK + r0];
        const int kn1 = nbase + sIdx[qq * KK + r0 + 16];
        const float4* f0 = (const float4*)(features + (size_t)kn0 * CC + gc * 8);
        const float4* f1 = (const float4*)(features + (size_t)kn1 * CC + gc * 8);
        const float4 a = f0[0], b = f0[1], c = f1[0], d = f1[1];
        short8 v;
        v[0]=f2bs(a.x); v[1]=f2bs(a.y); v[2]=f2bs(a.z); v[3]=f2bs(a.w);
        v[4]=f2bs(b.x); v[5]=f2bs(b.y); v[6]=f2bs(b.z); v[7]=f2bs(b.w);
        *(short8*)&sA[buf][r0 * CC + pc * 8] = v;
        v[0]=f2bs(c.x); v[1]=f2bs(c.y); v[2]=f2bs(c.z); v[3]=f2bs(c.w);
        v[4]=f2bs(d.x); v[5]=f2bs(d.y); v[6]=f2bs(d.z); v[7]=f2bs(d.w);
        *(short8*)&sA[buf][(r0 + 16) * CC + pc * 8] = v;
    };
    auto geo_store = [&](int qq) {
        if (lane < 8) {
            const int j = wv * 8 + lane, s = qq % 3, b = qq % 3;
            const float cx = sCtr[qq * 3], cy = sCtr[qq * 3 + 1], cz = sCtr[qq * 3 + 2];
            const float gx = geoS[s][0], gy = geoS[s][1], gz = geoS[s][2];
            const float dx = gx - cx, dy = gy - cy, dz = gz - cz;
            const float dist = sqrtf(dx * dx + dy * dy + dz * dz);
            short8 v0, v1 = (short8)0;
            v0[0]=f2bs(cx); v0[1]=f2bs(cy); v0[2]=f2bs(cz);
            v0[3]=f2bs(gx); v0[4]=f2bs(gy); v0[5]=f2bs(gz);
            v0[6]=f2bs(dx); v0[7]=f2bs(dy);
            v1[0]=f2bs(dz); v1[1]=f2bs(dist);
            *(short8*)&sG[b][j * SG2 + 0] = v0;
            *(short8*)&sG[b][j * SG2 + 8] = v1;
        }
    };

    int offA[4];
    #pragma unroll
    for (int ks = 0; ks < 4; ++ks) offA[ks] = m * CC + (((ks * 4 + quad) ^ m) * 8);
    const int offG = m * SG2 + quad * 8;

    geo_load(0); stage(0);
    geo_load(1); stage(1);
    geo_load(2); stage(2);
    geo_store(0); geo_store(1);
    __syncthreads();

    #pragma unroll
    for (int p = 0; p < GRP; ++p) {
        if (p > 0) {
            asm volatile("s_waitcnt lgkmcnt(0)" ::: "memory");
            __builtin_amdgcn_s_barrier();
        }
        __builtin_amdgcn_sched_barrier(0);
        if (p + 3 < GRP) { geo_load(p + 3); stage(p + 3); }

        const short* ab = sA[p & 3];
        const short* ag = sG[p % 3];
        float4v acc[2][2] = {};
        #pragma unroll
        for (int ks = 0; ks < 4; ++ks) {
            const short8 a0 = *(const short8*)(ab + offA[ks]);
            const short8 a1 = *(const short8*)(ab + offA[ks] + 16 * CC);
            acc[0][0] = MFMA(a0, bWp[ks][0], acc[0][0], 0, 0, 0);
            acc[0][1] = MFMA(a0, bWp[ks][1], acc[0][1], 0, 0, 0);
            acc[1][0] = MFMA(a1, bWp[ks][0], acc[1][0], 0, 0, 0);
            acc[1][1] = MFMA(a1, bWp[ks][1], acc[1][1], 0, 0, 0);
        }
        short8 ga0 = (short8)0, ga1 = (short8)0;
        if (quad < 2) {
            ga0 = *(const short8*)(ag + offG);
            ga1 = *(const short8*)(ag + offG + 16 * SG2);
        }
        acc[0][0] = MFMA(ga0, bWp[4][0], acc[0][0], 0, 0, 0);
        acc[0][1] = MFMA(ga0, bWp[4][1], acc[0][1], 0, 0, 0);
        acc[1][0] = MFMA(ga1, bWp[4][0], acc[1][0], 0, 0, 0);
        acc[1][1] = MFMA(ga1, bWp[4][1], acc[1][1], 0, 0, 0);

        #pragma unroll
        for (int ntl = 0; ntl < 2; ++ntl) {
            float v = acc[0][ntl][0];
            #pragma unroll
            for (int rr = 1; rr < 4; ++rr) v = fmaxf(v, acc[0][ntl][rr]);
            #pragma unroll
            for (int rr = 0; rr < 4; ++rr) v = fmaxf(v, acc[1][ntl][rr]);
            v = fmaxf(v, __shfl_xor(v, 16));
            v = fmaxf(v, __shfl_xor(v, 32));
            v = fmaxf(v + beffv[ntl], 0.f);
            if (quad == 0) {
                const float fc = bs2f((ushort_t)sResF[p * CC + col0 + ntl * 16]);
                sRes[p * SR + col0 + ntl * 16] = f2bs(v + fc);
            }
        }
        if (p + 2 < GRP) geo_store(p + 2);
    }

    __syncthreads();

    short8 bWo[4][2];
    #pragma unroll
    for (int ks = 0; ks < 4; ++ks)
        #pragma unroll
        for (int ntl = 0; ntl < 2; ++ntl)
            bWo[ks][ntl] = *((const short8*)wsWo + ((ks * 4 + quad) * 128 + col0 + ntl * 16));

    const short* rm = sRes + m * SR;
    float4v acc2[2] = {};
    #pragma unroll
    for (int ks = 0; ks < 4; ++ks) {
        const short8 a = *(const short8*)(rm + ks * 32 + quad * 8);
        acc2[0] = MFMA(a, bWo[ks][0], acc2[0], 0, 0, 0);
        acc2[1] = MFMA(a, bWo[ks][1], acc2[1], 0, 0, 0);
    }
    const float boutv[2] = { b_out[col0], b_out[col0 + 16] };
    const float lngv[2]  = { ln_g[col0], ln_g[col0 + 16] };
    const float lnbv[2]  = { ln_b[col0], ln_b[col0 + 16] };
    #pragma unroll
    for (int r = 0; r < 4; ++r) {
        const float o0 = acc2[0][r] + boutv[0];
        const float o1 = acc2[1][r] + boutv[1];
        float ss = o0 + o1, qq2 = o0 * o0 + o1 * o1;
        #pragma unroll
        for (int d = 1; d < 16; d <<= 1) { ss += __shfl_xor(ss, d); qq2 += __shfl_xor(qq2, d); }
        if (m == 0) { sPS[wv][quad * 4 + r] = ss; sPQ[wv][quad * 4 + r] = qq2; }
    }
    __syncthreads();
    #pragma unroll
    for (int r = 0; r < 4; ++r) {
        const int R = quad * 4 + r;
        const float S = sPS[0][R] + sPS[1][R] + sPS[2][R] + sPS[3][R];
        const float Q = sPQ[0][R] + sPQ[1][R] + sPQ[2][R] + sPQ[3][R];
        const float mu  = S * (1.f / 128.f);
        const float var = fmaxf(Q * (1.f / 128.f) - mu * mu, 0.f);
        const float rstd = rsqrtf(var + LN_EPS);
        const float o0 = acc2[0][r] + boutv[0];
        const float o1 = acc2[1][r] + boutv[1];
        const size_t base = (size_t)(g0 + R) * CC;
        out[base + col0]      = fmaxf((o0 - mu) * rstd * lngv[0] + lnbv[0], 0.f);
        out[base + col0 + 16] = fmaxf((o1 - mu) * rstd * lngv[1] + lnbv[1], 0.f);
    }
}

extern "C" void kernel_launch(void* const* d_in, const int* in_sizes, int n_in,
                              void* d_out, int out_size, void* d_ws, size_t ws_size,
                              hipStream_t stream) {
    const float* points   = (const float*)d_in[0];
    const float* features = (const float*)d_in[1];
    const int*   gidx     = (const int*)  d_in[2];
    const float* w_pos    = (const float*)d_in[3];
    const float* b_pos    = (const float*)d_in[4];
    const float* w_gcm    = (const float*)d_in[5];
    const float* b_gcm    = (const float*)d_in[6];
    const float* w_out    = (const float*)d_in[7];
    const float* b_out    = (const float*)d_in[8];
    const float* ln_g     = (const float*)d_in[9];
    const float* ln_b     = (const float*)d_in[10];
    float* out = (float*)d_out;
    char* ws = (char*)d_ws;

    if (ws_size >= WS_NEED) {
        ushort_t* wsFW   = (ushort_t*)(ws + WS_FW);
        short*    wsWo   = (short*)(ws + WS_WO);
        float*    wsBeff = (float*)(ws + WS_BE);
        short*    wsW4   = (short*)(ws + WS_W4);
        float*    wsWc   = (float*)(ws + WS_WC);
        short*    wsWpF  = (short*)(ws + WS_WPF);
        hipLaunchKernelGGL(prep_w, dim3(3), dim3(256), 0, stream,
                           w_gcm, w_out, w_pos, b_pos, b_gcm,
                           wsWpF, wsWo, wsBeff, wsW4, wsWc);
        hipLaunchKernelGGL(prep_fw, dim3(NPTS / GRP), dim3(256), 0, stream,
                           features, wsWpF, wsFW);
        hipLaunchKernelGGL(bridge_fw, dim3(NPTS / GRP), dim3(256), 0, stream,
                           points, features, gidx, wsWo, wsBeff, wsW4, wsWc, wsFW,
                           b_out, ln_g, ln_b, out);
    } else {
        short* wsWp   = (short*)(ws + FB_WP);
        short* wsWo   = (short*)(ws + FB_WO);
        float* wsBeff = (float*)(ws + FB_BE);
        float* wsPG   = (float*)(ws + FB_PG);
        hipLaunchKernelGGL(prep_fold_fb, dim3(11), dim3(128), 0, stream,
                           w_pos, b_pos, w_gcm, b_gcm, wsPG, wsBeff);
        hipLaunchKernelGGL(prep_pack_fb, dim3(3), dim3(256), 0, stream,
                           w_gcm, w_out, wsPG, wsWp, wsWo);
        hipLaunchKernelGGL(bridge_fb, dim3(NPTS / GRP), dim3(256), 0, stream,
                           points, features, gidx, wsWp, wsWo, wsBeff,
                           b_out, ln_g, ln_b, out);
    }
}

// Round 6
// 149.481 us; speedup vs baseline: 1.1321x; 1.1321x over previous
//
#include <hip/hip_runtime.h>
#include <hip/hip_bf16.h>
#include <math.h>

typedef __attribute__((ext_vector_type(8))) short short8;
typedef __attribute__((ext_vector_type(4))) short short4v;
typedef __attribute__((ext_vector_type(4))) float float4v;
typedef __attribute__((ext_vector_type(2))) unsigned int uint2v;
typedef unsigned short ushort_t;

constexpr int NPTS = 32768;  // B*N
constexpr int NN   = 16384;  // points per batch
constexpr int KK   = 32;     // neighbors
constexpr int CC   = 128;    // channels
constexpr int GRP  = 16;     // points per block -> grid 2048
constexpr int SR   = 136;    // res LDS row stride (shorts)
constexpr int SG2  = 24;     // fallback geo stride
#define LN_EPS 1e-5f
#define MFMA   __builtin_amdgcn_mfma_f32_16x16x32_bf16
#define GLL(src, dst, sz) __builtin_amdgcn_global_load_lds( \
    (const __attribute__((address_space(1))) void*)(src),   \
    (__attribute__((address_space(3))) void*)(dst), sz, 0, 0)

// ---- new-path workspace layout ----
constexpr size_t WS_FW  = 0;                       // FW bf16: 32768*128*2 = 8388608
constexpr size_t WS_WO  = (size_t)NPTS * CC * 2;   // w_out frag-packed: 32768 B
constexpr size_t WS_BE  = WS_WO + 32768;           // beff: 512 B
constexpr size_t WS_WPF = WS_BE + 512;             // w_gcm frag-packed: 32768 B
constexpr size_t WS_PG  = WS_WPF + 32768;          // PG = w_pos@w_gcm: 10*128 f32 = 5120 B
constexpr size_t WS_NEED = WS_PG + 5120;           // 8459776 < 8467968 (known available)
// ---- fallback workspace layout (old scheme, small) ----
constexpr size_t FB_WP = 0, FB_WO = 40960, FB_BE = 73728, FB_PG = 74240;

__device__ __forceinline__ short f2bs(float x) {
    return (short)__builtin_bit_cast(unsigned short, __float2bfloat16(x));
}
__device__ __forceinline__ float bs2f(ushort_t u) {
    return __uint_as_float(((unsigned)u) << 16);
}

// ================= prep1: all weight packs, 13 independent blocks =================
// blk 0: wsWpF = w_gcm frag-packed; blk 1: wsWo = w_out frag-packed;
// blk 2..11: wsPG[g=blk-2] = w_pos[g] @ w_gcm (128-iter/thread, champion-style);
// blk 12: beff = b_gcm + b_pos @ w_gcm.
__global__ __launch_bounds__(256) void prep1(
    const float* __restrict__ w_gcm, const float* __restrict__ w_out,
    const float* __restrict__ w_pos, const float* __restrict__ b_pos,
    const float* __restrict__ b_gcm,
    short* __restrict__ wsWpF, short* __restrict__ wsWo,
    float* __restrict__ wsBeff, float* __restrict__ wsPG)
{
    const int t = threadIdx.x, blk = blockIdx.x;
    if (blk == 0) {
        #pragma unroll 4
        for (int e = t; e < 16 * 128 * 8; e += 256) {
            const int j = e & 7, n = (e >> 3) & 127, g = e >> 10;
            wsWpF[e] = f2bs(w_gcm[(g * 8 + j) * 128 + n]);
        }
    } else if (blk == 1) {
        #pragma unroll 4
        for (int e = t; e < 128 * 128; e += 256) {
            const int j = e & 7, n = (e >> 3) & 127, g = e >> 10;
            wsWo[e] = f2bs(w_out[(g * 8 + j) * 128 + n]);
        }
    } else if (blk < 12) {
        if (t < 128) {
            const int g = blk - 2, c = t;
            float s = 0.f;
            #pragma unroll
            for (int r = 0; r < 128; ++r) s += w_pos[g * 128 + r] * w_gcm[r * 128 + c];
            wsPG[g * 128 + c] = s;
        }
    } else {
        if (t < 128) {
            const int c = t;
            float sb = b_gcm[c];
            #pragma unroll
            for (int r = 0; r < 128; ++r) sb += b_pos[r] * w_gcm[r * 128 + c];
            wsBeff[c] = sb;
        }
    }
}

// ================= prep B: FW = features @ w_gcm (bf16), 16 rows/block =================
__global__ __launch_bounds__(256) void prep_fw(
    const float* __restrict__ features, const short* __restrict__ wsWpF,
    ushort_t* __restrict__ wsFW)
{
    const int t = threadIdx.x, blk = blockIdx.x;
    __shared__ short sF[16 * SR];
    const int g0 = blk * GRP;
    {   // stage features tile (f32 -> bf16), coalesced
        const int row = t >> 4, c8 = (t & 15) * 8;
        const float* fp = features + (size_t)(g0 + row) * CC + c8;
        const float4 a = *(const float4*)fp;
        const float4 b = *(const float4*)(fp + 4);
        short8 v;
        v[0]=f2bs(a.x); v[1]=f2bs(a.y); v[2]=f2bs(a.z); v[3]=f2bs(a.w);
        v[4]=f2bs(b.x); v[5]=f2bs(b.y); v[6]=f2bs(b.z); v[7]=f2bs(b.w);
        *(short8*)&sF[row * SR + c8] = v;
    }
    const int wv = t >> 6, lane = t & 63, quad = (lane >> 4) & 3, m = lane & 15;
    const int col0 = wv * 32 + m;
    short8 bf[4][2];
    #pragma unroll
    for (int ks = 0; ks < 4; ++ks) {
        bf[ks][0] = *((const short8*)wsWpF + ((ks * 4 + quad) * 128 + col0));
        bf[ks][1] = *((const short8*)wsWpF + ((ks * 4 + quad) * 128 + col0 + 16));
    }
    __syncthreads();
    float4v acc[2] = {};
    #pragma unroll
    for (int ks = 0; ks < 4; ++ks) {
        const short8 a = *(const short8*)(sF + m * SR + ks * 32 + quad * 8);
        acc[0] = MFMA(a, bf[ks][0], acc[0], 0, 0, 0);
        acc[1] = MFMA(a, bf[ks][1], acc[1], 0, 0, 0);
    }
    #pragma unroll
    for (int r = 0; r < 4; ++r) {
        const int R = quad * 4 + r;
        wsFW[(size_t)(g0 + R) * CC + col0]      = (ushort_t)f2bs(acc[0][r]);
        wsFW[(size_t)(g0 + R) * CC + col0 + 16] = (ushort_t)f2bs(acc[1][r]);
    }
}

// ================= main kernel: barrier-free FW-gather + rank-4 geo MFMA =================
// tr-read semantics (verified R5): lane fetches its own 8B chunk at addr = base+lane*8;
// out(l,j) = chunk(j*4 + ((l&15)>>2))[(l&15)&3] per 16-lane group. DMA roles rbL/jL/hL
// lay FW so out(q,m,r) = FW[k=q*4+r][wave-ch m] at region offsets {0,512,1024,1536}.
// Depth-3 prefetch (4 buffers, steady vmcnt(6)); w4f/wc derived from wsPG in prologue.
__global__ __launch_bounds__(256, 3) void bridge_fw(
    const float* __restrict__ points, const float* __restrict__ features,
    const int*   __restrict__ gidx,
    const short* __restrict__ wsWo, const float* __restrict__ wsBeff,
    const float* __restrict__ wsPG, const ushort_t* __restrict__ wsFW,
    const float* __restrict__ b_out, const float* __restrict__ ln_g,
    const float* __restrict__ ln_b, float* __restrict__ out)
{
    __shared__ short sA[4][4][1024];      // [wave][buf] gathered FW tiles (32 KB)
    __shared__ float sGxyz[GRP * KK * 3]; // all neighbor xyz (6 KB)
    __shared__ short sRes[GRP * SR];
    __shared__ short sResF[GRP * CC];
    __shared__ int   sIdx[GRP * KK];
    __shared__ float sCtr[GRP * 3];
    __shared__ float sPS[4][GRP], sPQ[4][GRP];

    const int t = threadIdx.x, wv = t >> 6, lane = t & 63;
    const int q = (lane >> 4) & 3, m = lane & 15;
    const int g0 = blockIdx.x * GRP;
    const int nbase = (g0 >= NN) ? NN : 0;
    const int colA = wv * 32 + m;
    const int rbL = lane >> 3, jL = (lane & 7) >> 1, hL = lane & 1;  // DMA lane roles

    // ---- prologue staging (plain loads; drained by the one __syncthreads) ----
    {
        const int gA = gidx[(size_t)g0 * KK + t];
        const int gB = gidx[(size_t)g0 * KK + t + 256];
        sIdx[t] = gA; sIdx[t + 256] = gB;
        const float* pA = points + (size_t)(nbase + gA) * 3;
        const float* pB = points + (size_t)(nbase + gB) * 3;
        sGxyz[t * 3 + 0] = pA[0]; sGxyz[t * 3 + 1] = pA[1]; sGxyz[t * 3 + 2] = pA[2];
        sGxyz[(t + 256) * 3 + 0] = pB[0];
        sGxyz[(t + 256) * 3 + 1] = pB[1];
        sGxyz[(t + 256) * 3 + 2] = pB[2];
    }
    if (t < GRP * 3) sCtr[t] = points[(size_t)g0 * 3 + t];
    {   // residual features f32 -> bf16
        const int row = t >> 4, c8 = (t & 15) * 8;
        const float* fp = features + (size_t)(g0 + row) * CC + c8;
        const float4 a = *(const float4*)fp;
        const float4 b = *(const float4*)(fp + 4);
        short8 v;
        v[0]=f2bs(a.x); v[1]=f2bs(a.y); v[2]=f2bs(a.z); v[3]=f2bs(a.w);
        v[4]=f2bs(b.x); v[5]=f2bs(b.y); v[6]=f2bs(b.z); v[7]=f2bs(b.w);
        *(short8*)&sResF[row * CC + c8] = v;
    }

    const float beffv[2] = { wsBeff[colA], wsBeff[colA + 16] };
    // derive per-column geo weights from wsPG (L2-hot, coalesced):
    //   wc[i]  = PG[i][c] - PG[6+i][c]           (center columns)
    //   w4     = {PG[3]+PG[6], PG[4]+PG[7], PG[5]+PG[8], PG[9]}[c]  (neighbor+dist)
    float wc[6];
    short8 w4f[2];
    #pragma unroll
    for (int n = 0; n < 2; ++n) {
        const int c = colA + n * 16;
        const float p0 = wsPG[0*128+c], p1 = wsPG[1*128+c], p2 = wsPG[2*128+c];
        const float p3 = wsPG[3*128+c], p4 = wsPG[4*128+c], p5 = wsPG[5*128+c];
        const float p6 = wsPG[6*128+c], p7 = wsPG[7*128+c], p8 = wsPG[8*128+c];
        const float p9 = wsPG[9*128+c];
        wc[n*3+0] = p0 - p6; wc[n*3+1] = p1 - p7; wc[n*3+2] = p2 - p8;
        short8 w = (short8)0;
        w[0] = f2bs(p3 + p6); w[1] = f2bs(p4 + p7); w[2] = f2bs(p5 + p8); w[3] = f2bs(p9);
        w4f[n] = (q == 0) ? w : (short8)0;
    }
    // per-lane tr address: base + lane*8 (verified R5)
    const unsigned trBase = (unsigned)(size_t)(__attribute__((address_space(3))) short*)&sA[wv][0][0]
                          + (unsigned)(lane * 8);

    __syncthreads();   // drains ALL prologue vmem; only block-wide barrier before the tail

    auto issue_fw = [&](int p, int buf) {
        // lane (rb, j2, h) fetches row k=rb*4+j2, channels [h*8,h*8+8) (+16ch in GLL1)
        const int kw = nbase + sIdx[p * KK + rbL * 4 + jL];
        const ushort_t* s0 = wsFW + (size_t)kw * CC + wv * 32 + hL * 8;
        GLL(s0,      &sA[wv][buf][0],   16);
        GLL(s0 + 16, &sA[wv][buf][512], 16);
    };

    issue_fw(0, 0);
    issue_fw(1, 1);
    issue_fw(2, 2);

    #pragma unroll
    for (int p = 0; p < GRP; ++p) {
        const int buf = p & 3;
        if (p + 3 < GRP) issue_fw(p + 3, (p + 3) & 3);
        // in-loop vmem stream is ONLY the GLLs -> counts exact (2 per point, depth-3)
        if (p + 3 < GRP)      asm volatile("s_waitcnt vmcnt(6)" ::: "memory");
        else if (p + 2 < GRP) asm volatile("s_waitcnt vmcnt(4)" ::: "memory");
        else if (p + 1 < GRP) asm volatile("s_waitcnt vmcnt(2)" ::: "memory");
        else                  asm volatile("s_waitcnt vmcnt(0)" ::: "memory");
        __builtin_amdgcn_sched_barrier(0);

        // C fragments: FW[k=q*4+r][colA(+16)] via hardware transpose read
        uint2v t00, t10, t01, t11;
        const unsigned trA = trBase + (unsigned)(buf * 2048);
        asm volatile("ds_read_b64_tr_b16 %0, %1 offset:0"    : "=&v"(t00) : "v"(trA));
        asm volatile("ds_read_b64_tr_b16 %0, %1 offset:512"  : "=&v"(t10) : "v"(trA));
        asm volatile("ds_read_b64_tr_b16 %0, %1 offset:1024" : "=&v"(t01) : "v"(trA));
        asm volatile("ds_read_b64_tr_b16 %0, %1 offset:1536" : "=&v"(t11) : "v"(trA));

        const float pcx = sCtr[p * 3], pcy = sCtr[p * 3 + 1], pcz = sCtr[p * 3 + 2];
        short8 ga0 = (short8)0, ga1 = (short8)0;
        if (q == 0) {   // folded geo A-frag: k-dims {gx, gy, gz, dist}
            const int i0 = (p * KK + m) * 3, i1 = i0 + 48;
            const float ax = sGxyz[i0], ay = sGxyz[i0 + 1], az = sGxyz[i0 + 2];
            const float bx = sGxyz[i1], by = sGxyz[i1 + 1], bz = sGxyz[i1 + 2];
            const float d0x = ax - pcx, d0y = ay - pcy, d0z = az - pcz;
            const float d1x = bx - pcx, d1y = by - pcy, d1z = bz - pcz;
            const float s0 = sqrtf(d0x * d0x + d0y * d0y + d0z * d0z);
            const float s1 = sqrtf(d1x * d1x + d1y * d1y + d1z * d1z);
            ga0[0]=f2bs(ax); ga0[1]=f2bs(ay); ga0[2]=f2bs(az); ga0[3]=f2bs(s0);
            ga1[0]=f2bs(bx); ga1[1]=f2bs(by); ga1[2]=f2bs(bz); ga1[3]=f2bs(s1);
        }

        asm volatile("s_waitcnt lgkmcnt(0)" ::: "memory");   // tr-reads complete
        __builtin_amdgcn_sched_barrier(0);                   // rule #18: pin consumers below

        // unpack gathered FW (bf16 -> f32) as MFMA C-input
        float4v c00, c10, c01, c11;
        c00[0]=__uint_as_float(t00[0] << 16); c00[1]=__uint_as_float(t00[0] & 0xffff0000u);
        c00[2]=__uint_as_float(t00[1] << 16); c00[3]=__uint_as_float(t00[1] & 0xffff0000u);
        c10[0]=__uint_as_float(t10[0] << 16); c10[1]=__uint_as_float(t10[0] & 0xffff0000u);
        c10[2]=__uint_as_float(t10[1] << 16); c10[3]=__uint_as_float(t10[1] & 0xffff0000u);
        c01[0]=__uint_as_float(t01[0] << 16); c01[1]=__uint_as_float(t01[0] & 0xffff0000u);
        c01[2]=__uint_as_float(t01[1] << 16); c01[3]=__uint_as_float(t01[1] & 0xffff0000u);
        c11[0]=__uint_as_float(t11[0] << 16); c11[1]=__uint_as_float(t11[0] & 0xffff0000u);
        c11[2]=__uint_as_float(t11[1] << 16); c11[3]=__uint_as_float(t11[1] & 0xffff0000u);

        c00 = MFMA(ga0, w4f[0], c00, 0, 0, 0);
        c01 = MFMA(ga0, w4f[1], c01, 0, 0, 0);
        c10 = MFMA(ga1, w4f[0], c10, 0, 0, 0);
        c11 = MFMA(ga1, w4f[1], c11, 0, 0, 0);

        const float cb0 = pcx * wc[0] + pcy * wc[1] + pcz * wc[2];
        const float cb1 = pcx * wc[3] + pcy * wc[4] + pcz * wc[5];

        // max over 8 values per ntl, nested triples -> v_max3_f32 fusion (T17)
        float v0 = fmaxf(fmaxf(fmaxf(c00[0], c00[1]), fmaxf(c00[2], c00[3])),
                         fmaxf(fmaxf(c10[0], c10[1]), fmaxf(c10[2], c10[3])));
        float v1 = fmaxf(fmaxf(fmaxf(c01[0], c01[1]), fmaxf(c01[2], c01[3])),
                         fmaxf(fmaxf(c11[0], c11[1]), fmaxf(c11[2], c11[3])));
        v0 = fmaxf(v0, __shfl_xor(v0, 16)); v0 = fmaxf(v0, __shfl_xor(v0, 32));
        v1 = fmaxf(v1, __shfl_xor(v1, 16)); v1 = fmaxf(v1, __shfl_xor(v1, 32));
        v0 = fmaxf(v0 + beffv[0] + cb0, 0.f);
        v1 = fmaxf(v1 + beffv[1] + cb1, 0.f);
        if (q == 0) {
            sRes[p * SR + colA]      = f2bs(v0 + bs2f((ushort_t)sResF[p * CC + colA]));
            sRes[p * SR + colA + 16] = f2bs(v1 + bs2f((ushort_t)sResF[p * CC + colA + 16]));
        }
    }

    __syncthreads();

    // ---- out projection: res(16x128) @ w_out(128x128) + LN + relu ----
    short8 bWo[4][2];
    #pragma unroll
    for (int ks = 0; ks < 4; ++ks)
        #pragma unroll
        for (int ntl = 0; ntl < 2; ++ntl)
            bWo[ks][ntl] = *((const short8*)wsWo + ((ks * 4 + q) * 128 + colA + ntl * 16));

    const short* rm = sRes + m * SR;
    float4v acc2[2] = {};
    #pragma unroll
    for (int ks = 0; ks < 4; ++ks) {
        const short8 a = *(const short8*)(rm + ks * 32 + q * 8);
        acc2[0] = MFMA(a, bWo[ks][0], acc2[0], 0, 0, 0);
        acc2[1] = MFMA(a, bWo[ks][1], acc2[1], 0, 0, 0);
    }

    const float boutv[2] = { b_out[colA], b_out[colA + 16] };
    const float lngv[2]  = { ln_g[colA], ln_g[colA + 16] };
    const float lnbv[2]  = { ln_b[colA], ln_b[colA + 16] };

    #pragma unroll
    for (int r = 0; r < 4; ++r) {
        const float o0 = acc2[0][r] + boutv[0];
        const float o1 = acc2[1][r] + boutv[1];
        float ss = o0 + o1, qq = o0 * o0 + o1 * o1;
        #pragma unroll
        for (int d = 1; d < 16; d <<= 1) { ss += __shfl_xor(ss, d); qq += __shfl_xor(qq, d); }
        if (m == 0) { sPS[wv][q * 4 + r] = ss; sPQ[wv][q * 4 + r] = qq; }
    }
    __syncthreads();

    #pragma unroll
    for (int r = 0; r < 4; ++r) {
        const int R = q * 4 + r;
        const float S = sPS[0][R] + sPS[1][R] + sPS[2][R] + sPS[3][R];
        const float Q = sPQ[0][R] + sPQ[1][R] + sPQ[2][R] + sPQ[3][R];
        const float mu  = S * (1.f / 128.f);
        const float var = fmaxf(Q * (1.f / 128.f) - mu * mu, 0.f);
        const float rstd = rsqrtf(var + LN_EPS);
        const float o0 = acc2[0][r] + boutv[0];
        const float o1 = acc2[1][r] + boutv[1];
        const size_t base = (size_t)(g0 + R) * CC;
        out[base + colA]      = fmaxf((o0 - mu) * rstd * lngv[0] + lnbv[0], 0.f);
        out[base + colA + 16] = fmaxf((o1 - mu) * rstd * lngv[1] + lnbv[1], 0.f);
    }
}

// ================= fallback path (small workspace; R2-verified structure, f32) =================
__global__ __launch_bounds__(128) void prep_fold_fb(
    const float* __restrict__ w_pos, const float* __restrict__ b_pos,
    const float* __restrict__ w_gcm, const float* __restrict__ b_gcm,
    float* __restrict__ wsPG, float* __restrict__ wsBeff)
{
    const int c = threadIdx.x, g = blockIdx.x;
    if (g < 10) {
        float s = 0.f;
        for (int r = 0; r < 128; ++r) s += w_pos[g * 128 + r] * w_gcm[r * 128 + c];
        wsPG[g * 128 + c] = s;
    } else {
        float s = b_gcm[c];
        for (int r = 0; r < 128; ++r) s += b_pos[r] * w_gcm[r * 128 + c];
        wsBeff[c] = s;
    }
}

__global__ __launch_bounds__(256) void prep_pack_fb(
    const float* __restrict__ w_gcm, const float* __restrict__ w_out,
    const float* __restrict__ wsPG, short* __restrict__ wsWp, short* __restrict__ wsWo)
{
    const int t = threadIdx.x, blk = blockIdx.x;
    if (blk == 0) {
        #pragma unroll 4
        for (int e = t; e < 16 * 128 * 8; e += 256) {
            const int j = e & 7, n = (e >> 3) & 127, g = e >> 10;
            wsWp[e] = f2bs(w_gcm[(g * 8 + j) * 128 + n]);
        }
    } else if (blk == 1) {
        #pragma unroll 4
        for (int e2 = t; e2 < 4 * 128 * 8; e2 += 256) {
            const int e = 16 * 128 * 8 + e2;
            const int j = e & 7, n = (e >> 3) & 127, g = e >> 10;
            const int k = g * 8 + j;
            wsWp[e] = (k < 138) ? f2bs(wsPG[(k - 128) * 128 + n]) : (short)0;
        }
    } else {
        #pragma unroll 4
        for (int e = t; e < 128 * 128; e += 256) {
            const int j = e & 7, n = (e >> 3) & 127, g = e >> 10;
            wsWo[e] = f2bs(w_out[(g * 8 + j) * 128 + n]);
        }
    }
}

__global__ __launch_bounds__(256, 3) void bridge_fb(
    const float* __restrict__ points, const float* __restrict__ features,
    const int*   __restrict__ gidx,
    const short* __restrict__ wsWp, const short* __restrict__ wsWo,
    const float* __restrict__ wsBeff,
    const float* __restrict__ b_out, const float* __restrict__ ln_g,
    const float* __restrict__ ln_b, float* __restrict__ out)
{
    __shared__ short sA[4][KK * CC];
    __shared__ short sG[3][KK * SG2];
    __shared__ short sRes[GRP * SR];
    __shared__ short sResF[GRP * CC];
    __shared__ int   sIdx[GRP * KK];
    __shared__ float sCtr[GRP * 3];
    __shared__ float sPS[4][GRP], sPQ[4][GRP];

    const int t = threadIdx.x, wv = t >> 6, lane = t & 63;
    const int quad = (lane >> 4) & 3, m = lane & 15;
    const int g0 = blockIdx.x * GRP;
    const int nbase = (g0 >= NN) ? NN : 0;
    const int col0 = wv * 32 + m;

    sIdx[t]       = gidx[(size_t)g0 * KK + t];
    sIdx[t + 256] = gidx[(size_t)g0 * KK + t + 256];
    if (t < GRP * 3) sCtr[t] = points[(size_t)g0 * 3 + t];
    {
        const float* fs = features + (size_t)g0 * CC + t * 8;
        short8 v;
        #pragma unroll
        for (int i = 0; i < 8; ++i) v[i] = f2bs(fs[i]);
        *(short8*)&sResF[t * 8] = v;
    }

    short8 bWp[5][2];
    #pragma unroll
    for (int ks = 0; ks < 5; ++ks)
        #pragma unroll
        for (int ntl = 0; ntl < 2; ++ntl)
            bWp[ks][ntl] = *((const short8*)wsWp + ((ks * 4 + quad) * 128 + col0 + ntl * 16));
    const float beffv[2] = { wsBeff[col0], wsBeff[col0 + 16] };

    __syncthreads();

    const int r0 = wv * 4 + (lane >> 4);
    const int pc = lane & 15;
    const int gc = pc ^ r0;

    float geoS[3][3];

    auto geo_load = [&](int qq) {
        if (lane < 8) {
            const int j = wv * 8 + lane;
            const int kng = nbase + sIdx[qq * KK + j];
            const float* pp = points + (size_t)kng * 3;
            const int s = qq % 3;
            geoS[s][0] = pp[0]; geoS[s][1] = pp[1]; geoS[s][2] = pp[2];
        }
    };
    auto stage = [&](int qq) {
        const int buf = qq & 3;
        const int kn0 = nbase + sIdx[qq * KK + r0];
        const int kn1 = nbase + sIdx[qq * KK + r0 + 16];
        const float4* f0 = (const float4*)(features + (size_t)kn0 * CC + gc * 8);
        const float4* f1 = (const float4*)(features + (size_t)kn1 * CC + gc * 8);
        const float4 a = f0[0], b = f0[1], c = f1[0], d = f1[1];
        short8 v;
        v[0]=f2bs(a.x); v[1]=f2bs(a.y); v[2]=f2bs(a.z); v[3]=f2bs(a.w);
        v[4]=f2bs(b.x); v[5]=f2bs(b.y); v[6]=f2bs(b.z); v[7]=f2bs(b.w);
        *(short8*)&sA[buf][r0 * CC + pc * 8] = v;
        v[0]=f2bs(c.x); v[1]=f2bs(c.y); v[2]=f2bs(c.z); v[3]=f2bs(c.w);
        v[4]=f2bs(d.x); v[5]=f2bs(d.y); v[6]=f2bs(d.z); v[7]=f2bs(d.w);
        *(short8*)&sA[buf][(r0 + 16) * CC + pc * 8] = v;
    };
    auto geo_store = [&](int qq) {
        if (lane < 8) {
            const int j = wv * 8 + lane, s = qq % 3, b = qq % 3;
            const float cx = sCtr[qq * 3], cy = sCtr[qq * 3 + 1], cz = sCtr[qq * 3 + 2];
            const float gx = geoS[s][0], gy = geoS[s][1], gz = geoS[s][2];
            const float dx = gx - cx, dy = gy - cy, dz = gz - cz;
            const float dist = sqrtf(dx * dx + dy * dy + dz * dz);
            short8 v0, v1 = (short8)0;
            v0[0]=f2bs(cx); v0[1]=f2bs(cy); v0[2]=f2bs(cz);
            v0[3]=f2bs(gx); v0[4]=f2bs(gy); v0[5]=f2bs(gz);
            v0[6]=f2bs(dx); v0[7]=f2bs(dy);
            v1[0]=f2bs(dz); v1[1]=f2bs(dist);
            *(short8*)&sG[b][j * SG2 + 0] = v0;
            *(short8*)&sG[b][j * SG2 + 8] = v1;
        }
    };

    int offA[4];
    #pragma unroll
    for (int ks = 0; ks < 4; ++ks) offA[ks] = m * CC + (((ks * 4 + quad) ^ m) * 8);
    const int offG = m * SG2 + quad * 8;

    geo_load(0); stage(0);
    geo_load(1); stage(1);
    geo_load(2); stage(2);
    geo_store(0); geo_store(1);
    __syncthreads();

    #pragma unroll
    for (int p = 0; p < GRP; ++p) {
        if (p > 0) {
            asm volatile("s_waitcnt lgkmcnt(0)" ::: "memory");
            __builtin_amdgcn_s_barrier();
        }
        __builtin_amdgcn_sched_barrier(0);
        if (p + 3 < GRP) { geo_load(p + 3); stage(p + 3); }

        const short* ab = sA[p & 3];
        const short* ag = sG[p % 3];
        float4v acc[2][2] = {};
        #pragma unroll
        for (int ks = 0; ks < 4; ++ks) {
            const short8 a0 = *(const short8*)(ab + offA[ks]);
            const short8 a1 = *(const short8*)(ab + offA[ks] + 16 * CC);
            acc[0][0] = MFMA(a0, bWp[ks][0], acc[0][0], 0, 0, 0);
            acc[0][1] = MFMA(a0, bWp[ks][1], acc[0][1], 0, 0, 0);
            acc[1][0] = MFMA(a1, bWp[ks][0], acc[1][0], 0, 0, 0);
            acc[1][1] = MFMA(a1, bWp[ks][1], acc[1][1], 0, 0, 0);
        }
        short8 ga0 = (short8)0, ga1 = (short8)0;
        if (quad < 2) {
            ga0 = *(const short8*)(ag + offG);
            ga1 = *(const short8*)(ag + offG + 16 * SG2);
        }
        acc[0][0] = MFMA(ga0, bWp[4][0], acc[0][0], 0, 0, 0);
        acc[0][1] = MFMA(ga0, bWp[4][1], acc[0][1], 0, 0, 0);
        acc[1][0] = MFMA(ga1, bWp[4][0], acc[1][0], 0, 0, 0);
        acc[1][1] = MFMA(ga1, bWp[4][1], acc[1][1], 0, 0, 0);

        #pragma unroll
        for (int ntl = 0; ntl < 2; ++ntl) {
            float v = acc[0][ntl][0];
            #pragma unroll
            for (int rr = 1; rr < 4; ++rr) v = fmaxf(v, acc[0][ntl][rr]);
            #pragma unroll
            for (int rr = 0; rr < 4; ++rr) v = fmaxf(v, acc[1][ntl][rr]);
            v = fmaxf(v, __shfl_xor(v, 16));
            v = fmaxf(v, __shfl_xor(v, 32));
            v = fmaxf(v + beffv[ntl], 0.f);
            if (quad == 0) {
                const float fc = bs2f((ushort_t)sResF[p * CC + col0 + ntl * 16]);
                sRes[p * SR + col0 + ntl * 16] = f2bs(v + fc);
            }
        }
        if (p + 2 < GRP) geo_store(p + 2);
    }

    __syncthreads();

    short8 bWo[4][2];
    #pragma unroll
    for (int ks = 0; ks < 4; ++ks)
        #pragma unroll
        for (int ntl = 0; ntl < 2; ++ntl)
            bWo[ks][ntl] = *((const short8*)wsWo + ((ks * 4 + quad) * 128 + col0 + ntl * 16));

    const short* rm = sRes + m * SR;
    float4v acc2[2] = {};
    #pragma unroll
    for (int ks = 0; ks < 4; ++ks) {
        const short8 a = *(const short8*)(rm + ks * 32 + quad * 8);
        acc2[0] = MFMA(a, bWo[ks][0], acc2[0], 0, 0, 0);
        acc2[1] = MFMA(a, bWo[ks][1], acc2[1], 0, 0, 0);
    }
    const float boutv[2] = { b_out[col0], b_out[col0 + 16] };
    const float lngv[2]  = { ln_g[col0], ln_g[col0 + 16] };
    const float lnbv[2]  = { ln_b[col0], ln_b[col0 + 16] };
    #pragma unroll
    for (int r = 0; r < 4; ++r) {
        const float o0 = acc2[0][r] + boutv[0];
        const float o1 = acc2[1][r] + boutv[1];
        float ss = o0 + o1, qq2 = o0 * o0 + o1 * o1;
        #pragma unroll
        for (int d = 1; d < 16; d <<= 1) { ss += __shfl_xor(ss, d); qq2 += __shfl_xor(qq2, d); }
        if (m == 0) { sPS[wv][quad * 4 + r] = ss; sPQ[wv][quad * 4 + r] = qq2; }
    }
    __syncthreads();
    #pragma unroll
    for (int r = 0; r < 4; ++r) {
        const int R = quad * 4 + r;
        const float S = sPS[0][R] + sPS[1][R] + sPS[2][R] + sPS[3][R];
        const float Q = sPQ[0][R] + sPQ[1][R] + sPQ[2][R] + sPQ[3][R];
        const float mu  = S * (1.f / 128.f);
        const float var = fmaxf(Q * (1.f / 128.f) - mu * mu, 0.f);
        const float rstd = rsqrtf(var + LN_EPS);
        const float o0 = acc2[0][r] + boutv[0];
        const float o1 = acc2[1][r] + boutv[1];
        const size_t base = (size_t)(g0 + R) * CC;
        out[base + col0]      = fmaxf((o0 - mu) * rstd * lngv[0] + lnbv[0], 0.f);
        out[base + col0 + 16] = fmaxf((o1 - mu) * rstd * lngv[1] + lnbv[1], 0.f);
    }
}

extern "C" void kernel_launch(void* const* d_in, const int* in_sizes, int n_in,
                              void* d_out, int out_size, void* d_ws, size_t ws_size,
                              hipStream_t stream) {
    const float* points   = (const float*)d_in[0];
    const float* features = (const float*)d_in[1];
    const int*   gidx     = (const int*)  d_in[2];
    const float* w_pos    = (const float*)d_in[3];
    const float* b_pos    = (const float*)d_in[4];
    const float* w_gcm    = (const float*)d_in[5];
    const float* b_gcm    = (const float*)d_in[6];
    const float* w_out    = (const float*)d_in[7];
    const float* b_out    = (const float*)d_in[8];
    const float* ln_g     = (const float*)d_in[9];
    const float* ln_b     = (const float*)d_in[10];
    float* out = (float*)d_out;
    char* ws = (char*)d_ws;

    if (ws_size >= WS_NEED) {
        ushort_t* wsFW   = (ushort_t*)(ws + WS_FW);
        short*    wsWo   = (short*)(ws + WS_WO);
        float*    wsBeff = (float*)(ws + WS_BE);
        short*    wsWpF  = (short*)(ws + WS_WPF);
        float*    wsPG   = (float*)(ws + WS_PG);
        hipLaunchKernelGGL(prep1, dim3(13), dim3(256), 0, stream,
                           w_gcm, w_out, w_pos, b_pos, b_gcm,
                           wsWpF, wsWo, wsBeff, wsPG);
        hipLaunchKernelGGL(prep_fw, dim3(NPTS / GRP), dim3(256), 0, stream,
                           features, wsWpF, wsFW);
        hipLaunchKernelGGL(bridge_fw, dim3(NPTS / GRP), dim3(256), 0, stream,
                           points, features, gidx, wsWo, wsBeff, wsPG, wsFW,
                           b_out, ln_g, ln_b, out);
    } else {
        short* wsWp   = (short*)(ws + FB_WP);
        short* wsWo   = (short*)(ws + FB_WO);
        float* wsBeff = (float*)(ws + FB_BE);
        float* wsPG   = (float*)(ws + FB_PG);
        hipLaunchKernelGGL(prep_fold_fb, dim3(11), dim3(128), 0, stream,
                           w_pos, b_pos, w_gcm, b_gcm, wsPG, wsBeff);
        hipLaunchKernelGGL(prep_pack_fb, dim3(3), dim3(256), 0, stream,
                           w_gcm, w_out, wsPG, wsWp, wsWo);
        hipLaunchKernelGGL(bridge_fb, dim3(NPTS / GRP), dim3(256), 0, stream,
                           points, features, gidx, wsWp, wsWo, wsBeff,
                           b_out, ln_g, ln_b, out);
    }
}

// Round 7
// 142.625 us; speedup vs baseline: 1.1865x; 1.0481x over previous
//
#include <hip/hip_runtime.h>
#include <hip/hip_bf16.h>
#include <math.h>

typedef __attribute__((ext_vector_type(8))) short short8;
typedef __attribute__((ext_vector_type(4))) short short4v;
typedef __attribute__((ext_vector_type(4))) float float4v;
typedef __attribute__((ext_vector_type(2))) unsigned int uint2v;
typedef unsigned short ushort_t;

constexpr int NPTS = 32768;  // B*N
constexpr int NN   = 16384;  // points per batch
constexpr int KK   = 32;     // neighbors
constexpr int CC   = 128;    // channels
constexpr int GRP  = 16;     // points per block -> grid 2048
constexpr int SR   = 136;    // res LDS row stride (shorts)
constexpr int SG2  = 24;     // fallback geo stride
#define LN_EPS 1e-5f
#define MFMA   __builtin_amdgcn_mfma_f32_16x16x32_bf16
#define GLL(src, dst, sz) __builtin_amdgcn_global_load_lds( \
    (const __attribute__((address_space(1))) void*)(src),   \
    (__attribute__((address_space(3))) void*)(dst), sz, 0, 0)

// ---- new-path workspace layout ----
constexpr size_t WS_FW  = 0;                       // FW bf16: 32768*128*2 = 8388608
constexpr size_t WS_WO  = (size_t)NPTS * CC * 2;   // w_out frag-packed: 32768 B
constexpr size_t WS_BE  = WS_WO + 32768;           // beff: 512 B
constexpr size_t WS_WPF = WS_BE + 512;             // w_gcm frag-packed: 32768 B
constexpr size_t WS_PG  = WS_WPF + 32768;          // PG = w_pos@w_gcm: 10*128 f32 = 5120 B
constexpr size_t WS_NEED = WS_PG + 5120;           // 8459776 (known available)
// ---- fallback workspace layout (old scheme, small) ----
constexpr size_t FB_WP = 0, FB_WO = 40960, FB_BE = 73728, FB_PG = 74240;

__device__ __forceinline__ short f2bs(float x) {
    return (short)__builtin_bit_cast(unsigned short, __float2bfloat16(x));
}
__device__ __forceinline__ float bs2f(ushort_t u) {
    return __uint_as_float(((unsigned)u) << 16);
}

// ================= prep1: all weight packs, 13 independent blocks =================
__global__ __launch_bounds__(256) void prep1(
    const float* __restrict__ w_gcm, const float* __restrict__ w_out,
    const float* __restrict__ w_pos, const float* __restrict__ b_pos,
    const float* __restrict__ b_gcm,
    short* __restrict__ wsWpF, short* __restrict__ wsWo,
    float* __restrict__ wsBeff, float* __restrict__ wsPG)
{
    const int t = threadIdx.x, blk = blockIdx.x;
    if (blk == 0) {
        #pragma unroll 4
        for (int e = t; e < 16 * 128 * 8; e += 256) {
            const int j = e & 7, n = (e >> 3) & 127, g = e >> 10;
            wsWpF[e] = f2bs(w_gcm[(g * 8 + j) * 128 + n]);
        }
    } else if (blk == 1) {
        #pragma unroll 4
        for (int e = t; e < 128 * 128; e += 256) {
            const int j = e & 7, n = (e >> 3) & 127, g = e >> 10;
            wsWo[e] = f2bs(w_out[(g * 8 + j) * 128 + n]);
        }
    } else if (blk < 12) {
        if (t < 128) {
            const int g = blk - 2, c = t;
            float s = 0.f;
            #pragma unroll
            for (int r = 0; r < 128; ++r) s += w_pos[g * 128 + r] * w_gcm[r * 128 + c];
            wsPG[g * 128 + c] = s;
        }
    } else {
        if (t < 128) {
            const int c = t;
            float sb = b_gcm[c];
            #pragma unroll
            for (int r = 0; r < 128; ++r) sb += b_pos[r] * w_gcm[r * 128 + c];
            wsBeff[c] = sb;
        }
    }
}

// ================= prep B: FW = features @ w_gcm (bf16), 16 rows/block =================
__global__ __launch_bounds__(256) void prep_fw(
    const float* __restrict__ features, const short* __restrict__ wsWpF,
    ushort_t* __restrict__ wsFW)
{
    const int t = threadIdx.x, blk = blockIdx.x;
    __shared__ short sF[16 * SR];
    const int g0 = blk * GRP;
    {   // stage features tile (f32 -> bf16), coalesced
        const int row = t >> 4, c8 = (t & 15) * 8;
        const float* fp = features + (size_t)(g0 + row) * CC + c8;
        const float4 a = *(const float4*)fp;
        const float4 b = *(const float4*)(fp + 4);
        short8 v;
        v[0]=f2bs(a.x); v[1]=f2bs(a.y); v[2]=f2bs(a.z); v[3]=f2bs(a.w);
        v[4]=f2bs(b.x); v[5]=f2bs(b.y); v[6]=f2bs(b.z); v[7]=f2bs(b.w);
        *(short8*)&sF[row * SR + c8] = v;
    }
    const int wv = t >> 6, lane = t & 63, quad = (lane >> 4) & 3, m = lane & 15;
    const int col0 = wv * 32 + m;
    short8 bf[4][2];
    #pragma unroll
    for (int ks = 0; ks < 4; ++ks) {
        bf[ks][0] = *((const short8*)wsWpF + ((ks * 4 + quad) * 128 + col0));
        bf[ks][1] = *((const short8*)wsWpF + ((ks * 4 + quad) * 128 + col0 + 16));
    }
    __syncthreads();
    float4v acc[2] = {};
    #pragma unroll
    for (int ks = 0; ks < 4; ++ks) {
        const short8 a = *(const short8*)(sF + m * SR + ks * 32 + quad * 8);
        acc[0] = MFMA(a, bf[ks][0], acc[0], 0, 0, 0);
        acc[1] = MFMA(a, bf[ks][1], acc[1], 0, 0, 0);
    }
    #pragma unroll
    for (int r = 0; r < 4; ++r) {
        const int R = quad * 4 + r;
        wsFW[(size_t)(g0 + R) * CC + col0]      = (ushort_t)f2bs(acc[0][r]);
        wsFW[(size_t)(g0 + R) * CC + col0 + 16] = (ushort_t)f2bs(acc[1][r]);
    }
}

// ================= main kernel: barrier-free FW-gather + rank-4 geo MFMA =================
// R5-verified schedule (depth-2, 3 buffers, vmcnt 4/2/0) + occupancy bump:
// sResF eliminated (residual features held in 8 regs/lane, delivered at pool time
// via one __shfl from lane (p>>2)*16+m) -> LDS 37.8 KB -> 4 blocks/CU (16 waves).
__global__ __launch_bounds__(256, 4) void bridge_fw(
    const float* __restrict__ points, const float* __restrict__ features,
    const int*   __restrict__ gidx,
    const short* __restrict__ wsWo, const float* __restrict__ wsBeff,
    const float* __restrict__ wsPG, const ushort_t* __restrict__ wsFW,
    const float* __restrict__ b_out, const float* __restrict__ ln_g,
    const float* __restrict__ ln_b, float* __restrict__ out)
{
    __shared__ short sA[4][3][1024];      // [wave][buf] gathered FW tiles (24 KB)
    __shared__ float sGxyz[GRP * KK * 3]; // all neighbor xyz (6 KB)
    __shared__ short sRes[GRP * SR];      // 4.25 KB
    __shared__ int   sIdx[GRP * KK];      // 2 KB
    __shared__ float sCtr[GRP * 3];
    __shared__ float sPS[4][GRP], sPQ[4][GRP];

    const int t = threadIdx.x, wv = t >> 6, lane = t & 63;
    const int q = (lane >> 4) & 3, m = lane & 15;
    const int g0 = blockIdx.x * GRP;
    const int nbase = (g0 >= NN) ? NN : 0;
    const int colA = wv * 32 + m;
    const int rbL = lane >> 3, jL = (lane & 7) >> 1, hL = lane & 1;  // DMA lane roles

    // ---- prologue staging (plain loads; drained by the one __syncthreads) ----
    {
        const int gA = gidx[(size_t)g0 * KK + t];
        const int gB = gidx[(size_t)g0 * KK + t + 256];
        sIdx[t] = gA; sIdx[t + 256] = gB;
        const float* pA = points + (size_t)(nbase + gA) * 3;
        const float* pB = points + (size_t)(nbase + gB) * 3;
        sGxyz[t * 3 + 0] = pA[0]; sGxyz[t * 3 + 1] = pA[1]; sGxyz[t * 3 + 2] = pA[2];
        sGxyz[(t + 256) * 3 + 0] = pB[0];
        sGxyz[(t + 256) * 3 + 1] = pB[1];
        sGxyz[(t + 256) * 3 + 2] = pB[2];
    }
    if (t < GRP * 3) sCtr[t] = points[(size_t)g0 * 3 + t];

    // residual features -> registers (f32): lane (q,m) holds points q*4..q*4+3
    float rr[4][2];
    #pragma unroll
    for (int j = 0; j < 4; ++j) {
        const size_t pt = (size_t)(g0 + q * 4 + j) * CC;
        rr[j][0] = features[pt + colA];
        rr[j][1] = features[pt + colA + 16];
    }

    const float beffv[2] = { wsBeff[colA], wsBeff[colA + 16] };
    // per-column geo weights derived from wsPG (L2-hot):
    float wc[6];
    short8 w4f[2];
    #pragma unroll
    for (int n = 0; n < 2; ++n) {
        const int c = colA + n * 16;
        const float p0 = wsPG[0*128+c], p1 = wsPG[1*128+c], p2 = wsPG[2*128+c];
        const float p3 = wsPG[3*128+c], p4 = wsPG[4*128+c], p5 = wsPG[5*128+c];
        const float p6 = wsPG[6*128+c], p7 = wsPG[7*128+c], p8 = wsPG[8*128+c];
        const float p9 = wsPG[9*128+c];
        wc[n*3+0] = p0 - p6; wc[n*3+1] = p1 - p7; wc[n*3+2] = p2 - p8;
        short8 w = (short8)0;
        w[0] = f2bs(p3 + p6); w[1] = f2bs(p4 + p7); w[2] = f2bs(p5 + p8); w[3] = f2bs(p9);
        w4f[n] = (q == 0) ? w : (short8)0;
    }
    // per-lane tr address: base + lane*8 (verified R5)
    const unsigned trBase = (unsigned)(size_t)(__attribute__((address_space(3))) short*)&sA[wv][0][0]
                          + (unsigned)(lane * 8);

    __syncthreads();   // drains ALL prologue vmem; only block-wide barrier before the tail

    auto issue_fw = [&](int p, int buf) {
        // lane (rb, j2, h) fetches row k=rb*4+j2, channels [h*8,h*8+8) (+16ch in GLL1)
        const int kw = nbase + sIdx[p * KK + rbL * 4 + jL];
        const ushort_t* s0 = wsFW + (size_t)kw * CC + wv * 32 + hL * 8;
        GLL(s0,      &sA[wv][buf][0],   16);
        GLL(s0 + 16, &sA[wv][buf][512], 16);
    };

    issue_fw(0, 0);
    issue_fw(1, 1);

    #pragma unroll
    for (int p = 0; p < GRP; ++p) {
        const int buf = p % 3;
        if (p + 2 < GRP) issue_fw(p + 2, (p + 2) % 3);
        // in-loop vmem stream is ONLY the GLLs -> counts exact (2/point, depth-2)
        if (p + 2 < GRP)      asm volatile("s_waitcnt vmcnt(4)" ::: "memory");
        else if (p + 1 < GRP) asm volatile("s_waitcnt vmcnt(2)" ::: "memory");
        else                  asm volatile("s_waitcnt vmcnt(0)" ::: "memory");
        __builtin_amdgcn_sched_barrier(0);

        // C fragments: FW[k=q*4+r][colA(+16)] via hardware transpose read
        uint2v t00, t10, t01, t11;
        const unsigned trA = trBase + (unsigned)(buf * 2048);
        asm volatile("ds_read_b64_tr_b16 %0, %1 offset:0"    : "=&v"(t00) : "v"(trA));
        asm volatile("ds_read_b64_tr_b16 %0, %1 offset:512"  : "=&v"(t10) : "v"(trA));
        asm volatile("ds_read_b64_tr_b16 %0, %1 offset:1024" : "=&v"(t01) : "v"(trA));
        asm volatile("ds_read_b64_tr_b16 %0, %1 offset:1536" : "=&v"(t11) : "v"(trA));

        const float pcx = sCtr[p * 3], pcy = sCtr[p * 3 + 1], pcz = sCtr[p * 3 + 2];
        short8 ga0 = (short8)0, ga1 = (short8)0;
        if (q == 0) {   // folded geo A-frag: k-dims {gx, gy, gz, dist}
            const int i0 = (p * KK + m) * 3, i1 = i0 + 48;
            const float ax = sGxyz[i0], ay = sGxyz[i0 + 1], az = sGxyz[i0 + 2];
            const float bx = sGxyz[i1], by = sGxyz[i1 + 1], bz = sGxyz[i1 + 2];
            const float d0x = ax - pcx, d0y = ay - pcy, d0z = az - pcz;
            const float d1x = bx - pcx, d1y = by - pcy, d1z = bz - pcz;
            const float s0 = sqrtf(d0x * d0x + d0y * d0y + d0z * d0z);
            const float s1 = sqrtf(d1x * d1x + d1y * d1y + d1z * d1z);
            ga0[0]=f2bs(ax); ga0[1]=f2bs(ay); ga0[2]=f2bs(az); ga0[3]=f2bs(s0);
            ga1[0]=f2bs(bx); ga1[1]=f2bs(by); ga1[2]=f2bs(bz); ga1[3]=f2bs(s1);
        }

        asm volatile("s_waitcnt lgkmcnt(0)" ::: "memory");   // tr-reads complete
        __builtin_amdgcn_sched_barrier(0);                   // rule #18: pin consumers below

        // unpack gathered FW (bf16 -> f32) as MFMA C-input
        float4v c00, c10, c01, c11;
        c00[0]=__uint_as_float(t00[0] << 16); c00[1]=__uint_as_float(t00[0] & 0xffff0000u);
        c00[2]=__uint_as_float(t00[1] << 16); c00[3]=__uint_as_float(t00[1] & 0xffff0000u);
        c10[0]=__uint_as_float(t10[0] << 16); c10[1]=__uint_as_float(t10[0] & 0xffff0000u);
        c10[2]=__uint_as_float(t10[1] << 16); c10[3]=__uint_as_float(t10[1] & 0xffff0000u);
        c01[0]=__uint_as_float(t01[0] << 16); c01[1]=__uint_as_float(t01[0] & 0xffff0000u);
        c01[2]=__uint_as_float(t01[1] << 16); c01[3]=__uint_as_float(t01[1] & 0xffff0000u);
        c11[0]=__uint_as_float(t11[0] << 16); c11[1]=__uint_as_float(t11[0] & 0xffff0000u);
        c11[2]=__uint_as_float(t11[1] << 16); c11[3]=__uint_as_float(t11[1] & 0xffff0000u);

        c00 = MFMA(ga0, w4f[0], c00, 0, 0, 0);
        c01 = MFMA(ga0, w4f[1], c01, 0, 0, 0);
        c10 = MFMA(ga1, w4f[0], c10, 0, 0, 0);
        c11 = MFMA(ga1, w4f[1], c11, 0, 0, 0);

        const float cb0 = pcx * wc[0] + pcy * wc[1] + pcz * wc[2];
        const float cb1 = pcx * wc[3] + pcy * wc[4] + pcz * wc[5];

        float v0 = fmaxf(fmaxf(fmaxf(c00[0], c00[1]), fmaxf(c00[2], c00[3])),
                         fmaxf(fmaxf(c10[0], c10[1]), fmaxf(c10[2], c10[3])));
        float v1 = fmaxf(fmaxf(fmaxf(c01[0], c01[1]), fmaxf(c01[2], c01[3])),
                         fmaxf(fmaxf(c11[0], c11[1]), fmaxf(c11[2], c11[3])));
        v0 = fmaxf(v0, __shfl_xor(v0, 16)); v0 = fmaxf(v0, __shfl_xor(v0, 32));
        v1 = fmaxf(v1, __shfl_xor(v1, 16)); v1 = fmaxf(v1, __shfl_xor(v1, 32));
        v0 = fmaxf(v0 + beffv[0] + cb0, 0.f);
        v1 = fmaxf(v1 + beffv[1] + cb1, 0.f);

        // residual via register shuffle: holder lane = (p>>2)*16 + m, reg p&3
        const float fc0 = __shfl(rr[p & 3][0], ((p >> 2) << 4) + m);
        const float fc1 = __shfl(rr[p & 3][1], ((p >> 2) << 4) + m);
        if (q == 0) {
            sRes[p * SR + colA]      = f2bs(v0 + fc0);
            sRes[p * SR + colA + 16] = f2bs(v1 + fc1);
        }
    }

    __syncthreads();

    // ---- out projection: res(16x128) @ w_out(128x128) + LN + relu ----
    short8 bWo[4][2];
    #pragma unroll
    for (int ks = 0; ks < 4; ++ks)
        #pragma unroll
        for (int ntl = 0; ntl < 2; ++ntl)
            bWo[ks][ntl] = *((const short8*)wsWo + ((ks * 4 + q) * 128 + colA + ntl * 16));

    const short* rm = sRes + m * SR;
    float4v acc2[2] = {};
    #pragma unroll
    for (int ks = 0; ks < 4; ++ks) {
        const short8 a = *(const short8*)(rm + ks * 32 + q * 8);
        acc2[0] = MFMA(a, bWo[ks][0], acc2[0], 0, 0, 0);
        acc2[1] = MFMA(a, bWo[ks][1], acc2[1], 0, 0, 0);
    }

    const float boutv[2] = { b_out[colA], b_out[colA + 16] };
    const float lngv[2]  = { ln_g[colA], ln_g[colA + 16] };
    const float lnbv[2]  = { ln_b[colA], ln_b[colA + 16] };

    #pragma unroll
    for (int r = 0; r < 4; ++r) {
        const float o0 = acc2[0][r] + boutv[0];
        const float o1 = acc2[1][r] + boutv[1];
        float ss = o0 + o1, qq = o0 * o0 + o1 * o1;
        #pragma unroll
        for (int d = 1; d < 16; d <<= 1) { ss += __shfl_xor(ss, d); qq += __shfl_xor(qq, d); }
        if (m == 0) { sPS[wv][q * 4 + r] = ss; sPQ[wv][q * 4 + r] = qq; }
    }
    __syncthreads();

    #pragma unroll
    for (int r = 0; r < 4; ++r) {
        const int R = q * 4 + r;
        const float S = sPS[0][R] + sPS[1][R] + sPS[2][R] + sPS[3][R];
        const float Q = sPQ[0][R] + sPQ[1][R] + sPQ[2][R] + sPQ[3][R];
        const float mu  = S * (1.f / 128.f);
        const float var = fmaxf(Q * (1.f / 128.f) - mu * mu, 0.f);
        const float rstd = rsqrtf(var + LN_EPS);
        const float o0 = acc2[0][r] + boutv[0];
        const float o1 = acc2[1][r] + boutv[1];
        const size_t base = (size_t)(g0 + R) * CC;
        out[base + colA]      = fmaxf((o0 - mu) * rstd * lngv[0] + lnbv[0], 0.f);
        out[base + colA + 16] = fmaxf((o1 - mu) * rstd * lngv[1] + lnbv[1], 0.f);
    }
}

// ================= fallback path (small workspace; R2-verified structure, f32) =================
__global__ __launch_bounds__(128) void prep_fold_fb(
    const float* __restrict__ w_pos, const float* __restrict__ b_pos,
    const float* __restrict__ w_gcm, const float* __restrict__ b_gcm,
    float* __restrict__ wsPG, float* __restrict__ wsBeff)
{
    const int c = threadIdx.x, g = blockIdx.x;
    if (g < 10) {
        float s = 0.f;
        for (int r = 0; r < 128; ++r) s += w_pos[g * 128 + r] * w_gcm[r * 128 + c];
        wsPG[g * 128 + c] = s;
    } else {
        float s = b_gcm[c];
        for (int r = 0; r < 128; ++r) s += b_pos[r] * w_gcm[r * 128 + c];
        wsBeff[c] = s;
    }
}

__global__ __launch_bounds__(256) void prep_pack_fb(
    const float* __restrict__ w_gcm, const float* __restrict__ w_out,
    const float* __restrict__ wsPG, short* __restrict__ wsWp, short* __restrict__ wsWo)
{
    const int t = threadIdx.x, blk = blockIdx.x;
    if (blk == 0) {
        #pragma unroll 4
        for (int e = t; e < 16 * 128 * 8; e += 256) {
            const int j = e & 7, n = (e >> 3) & 127, g = e >> 10;
            wsWp[e] = f2bs(w_gcm[(g * 8 + j) * 128 + n]);
        }
    } else if (blk == 1) {
        #pragma unroll 4
        for (int e2 = t; e2 < 4 * 128 * 8; e2 += 256) {
            const int e = 16 * 128 * 8 + e2;
            const int j = e & 7, n = (e >> 3) & 127, g = e >> 10;
            const int k = g * 8 + j;
            wsWp[e] = (k < 138) ? f2bs(wsPG[(k - 128) * 128 + n]) : (short)0;
        }
    } else {
        #pragma unroll 4
        for (int e = t; e < 128 * 128; e += 256) {
            const int j = e & 7, n = (e >> 3) & 127, g = e >> 10;
            wsWo[e] = f2bs(w_out[(g * 8 + j) * 128 + n]);
        }
    }
}

__global__ __launch_bounds__(256, 3) void bridge_fb(
    const float* __restrict__ points, const float* __restrict__ features,
    const int*   __restrict__ gidx,
    const short* __restrict__ wsWp, const short* __restrict__ wsWo,
    const float* __restrict__ wsBeff,
    const float* __restrict__ b_out, const float* __restrict__ ln_g,
    const float* __restrict__ ln_b, float* __restrict__ out)
{
    __shared__ short sA[4][KK * CC];
    __shared__ short sG[3][KK * SG2];
    __shared__ short sRes[GRP * SR];
    __shared__ short sResF[GRP * CC];
    __shared__ int   sIdx[GRP * KK];
    __shared__ float sCtr[GRP * 3];
    __shared__ float sPS[4][GRP], sPQ[4][GRP];

    const int t = threadIdx.x, wv = t >> 6, lane = t & 63;
    const int quad = (lane >> 4) & 3, m = lane & 15;
    const int g0 = blockIdx.x * GRP;
    const int nbase = (g0 >= NN) ? NN : 0;
    const int col0 = wv * 32 + m;

    sIdx[t]       = gidx[(size_t)g0 * KK + t];
    sIdx[t + 256] = gidx[(size_t)g0 * KK + t + 256];
    if (t < GRP * 3) sCtr[t] = points[(size_t)g0 * 3 + t];
    {
        const float* fs = features + (size_t)g0 * CC + t * 8;
        short8 v;
        #pragma unroll
        for (int i = 0; i < 8; ++i) v[i] = f2bs(fs[i]);
        *(short8*)&sResF[t * 8] = v;
    }

    short8 bWp[5][2];
    #pragma unroll
    for (int ks = 0; ks < 5; ++ks)
        #pragma unroll
        for (int ntl = 0; ntl < 2; ++ntl)
            bWp[ks][ntl] = *((const short8*)wsWp + ((ks * 4 + quad) * 128 + col0 + ntl * 16));
    const float beffv[2] = { wsBeff[col0], wsBeff[col0 + 16] };

    __syncthreads();

    const int r0 = wv * 4 + (lane >> 4);
    const int pc = lane & 15;
    const int gc = pc ^ r0;

    float geoS[3][3];

    auto geo_load = [&](int qq) {
        if (lane < 8) {
            const int j = wv * 8 + lane;
            const int kng = nbase + sIdx[qq * KK + j];
            const float* pp = points + (size_t)kng * 3;
            const int s = qq % 3;
            geoS[s][0] = pp[0]; geoS[s][1] = pp[1]; geoS[s][2] = pp[2];
        }
    };
    auto stage = [&](int qq) {
        const int buf = qq & 3;
        const int kn0 = nbase + sIdx[qq * KK + r0];
        const int kn1 = nbase + sIdx[qq * KK + r0 + 16];
        const float4* f0 = (const float4*)(features + (size_t)kn0 * CC + gc * 8);
        const float4* f1 = (const float4*)(features + (size_t)kn1 * CC + gc * 8);
        const float4 a = f0[0], b = f0[1], c = f1[0], d = f1[1];
        short8 v;
        v[0]=f2bs(a.x); v[1]=f2bs(a.y); v[2]=f2bs(a.z); v[3]=f2bs(a.w);
        v[4]=f2bs(b.x); v[5]=f2bs(b.y); v[6]=f2bs(b.z); v[7]=f2bs(b.w);
        *(short8*)&sA[buf][r0 * CC + pc * 8] = v;
        v[0]=f2bs(c.x); v[1]=f2bs(c.y); v[2]=f2bs(c.z); v[3]=f2bs(c.w);
        v[4]=f2bs(d.x); v[5]=f2bs(d.y); v[6]=f2bs(d.z); v[7]=f2bs(d.w);
        *(short8*)&sA[buf][(r0 + 16) * CC + pc * 8] = v;
    };
    auto geo_store = [&](int qq) {
        if (lane < 8) {
            const int j = wv * 8 + lane, s = qq % 3, b = qq % 3;
            const float cx = sCtr[qq * 3], cy = sCtr[qq * 3 + 1], cz = sCtr[qq * 3 + 2];
            const float gx = geoS[s][0], gy = geoS[s][1], gz = geoS[s][2];
            const float dx = gx - cx, dy = gy - cy, dz = gz - cz;
            const float dist = sqrtf(dx * dx + dy * dy + dz * dz);
            short8 v0, v1 = (short8)0;
            v0[0]=f2bs(cx); v0[1]=f2bs(cy); v0[2]=f2bs(cz);
            v0[3]=f2bs(gx); v0[4]=f2bs(gy); v0[5]=f2bs(gz);
            v0[6]=f2bs(dx); v0[7]=f2bs(dy);
            v1[0]=f2bs(dz); v1[1]=f2bs(dist);
            *(short8*)&sG[b][j * SG2 + 0] = v0;
            *(short8*)&sG[b][j * SG2 + 8] = v1;
        }
    };

    int offA[4];
    #pragma unroll
    for (int ks = 0; ks < 4; ++ks) offA[ks] = m * CC + (((ks * 4 + quad) ^ m) * 8);
    const int offG = m * SG2 + quad * 8;

    geo_load(0); stage(0);
    geo_load(1); stage(1);
    geo_load(2); stage(2);
    geo_store(0); geo_store(1);
    __syncthreads();

    #pragma unroll
    for (int p = 0; p < GRP; ++p) {
        if (p > 0) {
            asm volatile("s_waitcnt lgkmcnt(0)" ::: "memory");
            __builtin_amdgcn_s_barrier();
        }
        __builtin_amdgcn_sched_barrier(0);
        if (p + 3 < GRP) { geo_load(p + 3); stage(p + 3); }

        const short* ab = sA[p & 3];
        const short* ag = sG[p % 3];
        float4v acc[2][2] = {};
        #pragma unroll
        for (int ks = 0; ks < 4; ++ks) {
            const short8 a0 = *(const short8*)(ab + offA[ks]);
            const short8 a1 = *(const short8*)(ab + offA[ks] + 16 * CC);
            acc[0][0] = MFMA(a0, bWp[ks][0], acc[0][0], 0, 0, 0);
            acc[0][1] = MFMA(a0, bWp[ks][1], acc[0][1], 0, 0, 0);
            acc[1][0] = MFMA(a1, bWp[ks][0], acc[1][0], 0, 0, 0);
            acc[1][1] = MFMA(a1, bWp[ks][1], acc[1][1], 0, 0, 0);
        }
        short8 ga0 = (short8)0, ga1 = (short8)0;
        if (quad < 2) {
            ga0 = *(const short8*)(ag + offG);
            ga1 = *(const short8*)(ag + offG + 16 * SG2);
        }
        acc[0][0] = MFMA(ga0, bWp[4][0], acc[0][0], 0, 0, 0);
        acc[0][1] = MFMA(ga0, bWp[4][1], acc[0][1], 0, 0, 0);
        acc[1][0] = MFMA(ga1, bWp[4][0], acc[1][0], 0, 0, 0);
        acc[1][1] = MFMA(ga1, bWp[4][1], acc[1][1], 0, 0, 0);

        #pragma unroll
        for (int ntl = 0; ntl < 2; ++ntl) {
            float v = acc[0][ntl][0];
            #pragma unroll
            for (int rr2 = 1; rr2 < 4; ++rr2) v = fmaxf(v, acc[0][ntl][rr2]);
            #pragma unroll
            for (int rr2 = 0; rr2 < 4; ++rr2) v = fmaxf(v, acc[1][ntl][rr2]);
            v = fmaxf(v, __shfl_xor(v, 16));
            v = fmaxf(v, __shfl_xor(v, 32));
            v = fmaxf(v + beffv[ntl], 0.f);
            if (quad == 0) {
                const float fc = bs2f((ushort_t)sResF[p * CC + col0 + ntl * 16]);
                sRes[p * SR + col0 + ntl * 16] = f2bs(v + fc);
            }
        }
        if (p + 2 < GRP) geo_store(p + 2);
    }

    __syncthreads();

    short8 bWo[4][2];
    #pragma unroll
    for (int ks = 0; ks < 4; ++ks)
        #pragma unroll
        for (int ntl = 0; ntl < 2; ++ntl)
            bWo[ks][ntl] = *((const short8*)wsWo + ((ks * 4 + quad) * 128 + col0 + ntl * 16));

    const short* rm = sRes + m * SR;
    float4v acc2[2] = {};
    #pragma unroll
    for (int ks = 0; ks < 4; ++ks) {
        const short8 a = *(const short8*)(rm + ks * 32 + quad * 8);
        acc2[0] = MFMA(a, bWo[ks][0], acc2[0], 0, 0, 0);
        acc2[1] = MFMA(a, bWo[ks][1], acc2[1], 0, 0, 0);
    }
    const float boutv[2] = { b_out[col0], b_out[col0 + 16] };
    const float lngv[2]  = { ln_g[col0], ln_g[col0 + 16] };
    const float lnbv[2]  = { ln_b[col0], ln_b[col0 + 16] };
    #pragma unroll
    for (int r = 0; r < 4; ++r) {
        const float o0 = acc2[0][r] + boutv[0];
        const float o1 = acc2[1][r] + boutv[1];
        float ss = o0 + o1, qq2 = o0 * o0 + o1 * o1;
        #pragma unroll
        for (int d = 1; d < 16; d <<= 1) { ss += __shfl_xor(ss, d); qq2 += __shfl_xor(qq2, d); }
        if (m == 0) { sPS[wv][quad * 4 + r] = ss; sPQ[wv][quad * 4 + r] = qq2; }
    }
    __syncthreads();
    #pragma unroll
    for (int r = 0; r < 4; ++r) {
        const int R = quad * 4 + r;
        const float S = sPS[0][R] + sPS[1][R] + sPS[2][R] + sPS[3][R];
        const float Q = sPQ[0][R] + sPQ[1][R] + sPQ[2][R] + sPQ[3][R];
        const float mu  = S * (1.f / 128.f);
        const float var = fmaxf(Q * (1.f / 128.f) - mu * mu, 0.f);
        const float rstd = rsqrtf(var + LN_EPS);
        const float o0 = acc2[0][r] + boutv[0];
        const float o1 = acc2[1][r] + boutv[1];
        const size_t base = (size_t)(g0 + R) * CC;
        out[base + col0]      = fmaxf((o0 - mu) * rstd * lngv[0] + lnbv[0], 0.f);
        out[base + col0 + 16] = fmaxf((o1 - mu) * rstd * lngv[1] + lnbv[1], 0.f);
    }
}

extern "C" void kernel_launch(void* const* d_in, const int* in_sizes, int n_in,
                              void* d_out, int out_size, void* d_ws, size_t ws_size,
                              hipStream_t stream) {
    const float* points   = (const float*)d_in[0];
    const float* features = (const float*)d_in[1];
    const int*   gidx     = (const int*)  d_in[2];
    const float* w_pos    = (const float*)d_in[3];
    const float* b_pos    = (const float*)d_in[4];
    const float* w_gcm    = (const float*)d_in[5];
    const float* b_gcm    = (const float*)d_in[6];
    const float* w_out    = (const float*)d_in[7];
    const float* b_out    = (const float*)d_in[8];
    const float* ln_g     = (const float*)d_in[9];
    const float* ln_b     = (const float*)d_in[10];
    float* out = (float*)d_out;
    char* ws = (char*)d_ws;

    if (ws_size >= WS_NEED) {
        ushort_t* wsFW   = (ushort_t*)(ws + WS_FW);
        short*    wsWo   = (short*)(ws + WS_WO);
        float*    wsBeff = (float*)(ws + WS_BE);
        short*    wsWpF  = (short*)(ws + WS_WPF);
        float*    wsPG   = (float*)(ws + WS_PG);
        hipLaunchKernelGGL(prep1, dim3(13), dim3(256), 0, stream,
                           w_gcm, w_out, w_pos, b_pos, b_gcm,
                           wsWpF, wsWo, wsBeff, wsPG);
        hipLaunchKernelGGL(prep_fw, dim3(NPTS / GRP), dim3(256), 0, stream,
                           features, wsWpF, wsFW);
        hipLaunchKernelGGL(bridge_fw, dim3(NPTS / GRP), dim3(256), 0, stream,
                           points, features, gidx, wsWo, wsBeff, wsPG, wsFW,
                           b_out, ln_g, ln_b, out);
    } else {
        short* wsWp   = (short*)(ws + FB_WP);
        short* wsWo   = (short*)(ws + FB_WO);
        float* wsBeff = (float*)(ws + FB_BE);
        float* wsPG   = (float*)(ws + FB_PG);
        hipLaunchKernelGGL(prep_fold_fb, dim3(11), dim3(128), 0, stream,
                           w_pos, b_pos, w_gcm, b_gcm, wsPG, wsBeff);
        hipLaunchKernelGGL(prep_pack_fb, dim3(3), dim3(256), 0, stream,
                           w_gcm, w_out, wsPG, wsWp, wsWo);
        hipLaunchKernelGGL(bridge_fb, dim3(NPTS / GRP), dim3(256), 0, stream,
                           points, features, gidx, wsWp, wsWo, wsBeff,
                           b_out, ln_g, ln_b, out);
    }
}

// Round 8
// 141.851 us; speedup vs baseline: 1.1930x; 1.0055x over previous
//
#include <hip/hip_runtime.h>
#include <hip/hip_bf16.h>
#include <math.h>

typedef __attribute__((ext_vector_type(8))) short short8;
typedef __attribute__((ext_vector_type(4))) short short4v;
typedef __attribute__((ext_vector_type(4))) float float4v;
typedef __attribute__((ext_vector_type(2))) unsigned int uint2v;
typedef unsigned short ushort_t;

constexpr int NPTS = 32768;  // B*N
constexpr int NN   = 16384;  // points per batch
constexpr int KK   = 32;     // neighbors
constexpr int CC   = 128;    // channels
constexpr int GRP  = 16;     // points per block -> grid 2048
constexpr int SR   = 136;    // res LDS row stride (shorts)
constexpr int SG2  = 24;     // fallback geo stride
#define LN_EPS 1e-5f
#define MFMA   __builtin_amdgcn_mfma_f32_16x16x32_bf16
#define GLL(src, dst, sz) __builtin_amdgcn_global_load_lds( \
    (const __attribute__((address_space(1))) void*)(src),   \
    (__attribute__((address_space(3))) void*)(dst), sz, 0, 0)

// ---- new-path workspace layout ----
constexpr size_t WS_FW  = 0;                       // FW bf16: 32768*128*2 = 8388608
constexpr size_t WS_WO  = (size_t)NPTS * CC * 2;   // w_out frag-packed: 32768 B
constexpr size_t WS_BE  = WS_WO + 32768;           // beff: 512 B
constexpr size_t WS_WPF = WS_BE + 512;             // w_gcm frag-packed: 32768 B
constexpr size_t WS_PG  = WS_WPF + 32768;          // PG = w_pos@w_gcm: 10*128 f32 = 5120 B
constexpr size_t WS_NEED = WS_PG + 5120;           // 8459776 (known available)
// ---- fallback workspace layout (old scheme, small) ----
constexpr size_t FB_WP = 0, FB_WO = 40960, FB_BE = 73728, FB_PG = 74240;

__device__ __forceinline__ short f2bs(float x) {
    return (short)__builtin_bit_cast(unsigned short, __float2bfloat16(x));
}
__device__ __forceinline__ float bs2f(ushort_t u) {
    return __uint_as_float(((unsigned)u) << 16);
}

// ================= prep1: all weight packs, 13 independent blocks =================
__global__ __launch_bounds__(256) void prep1(
    const float* __restrict__ w_gcm, const float* __restrict__ w_out,
    const float* __restrict__ w_pos, const float* __restrict__ b_pos,
    const float* __restrict__ b_gcm,
    short* __restrict__ wsWpF, short* __restrict__ wsWo,
    float* __restrict__ wsBeff, float* __restrict__ wsPG)
{
    const int t = threadIdx.x, blk = blockIdx.x;
    if (blk == 0) {
        #pragma unroll 4
        for (int e = t; e < 16 * 128 * 8; e += 256) {
            const int j = e & 7, n = (e >> 3) & 127, g = e >> 10;
            wsWpF[e] = f2bs(w_gcm[(g * 8 + j) * 128 + n]);
        }
    } else if (blk == 1) {
        #pragma unroll 4
        for (int e = t; e < 128 * 128; e += 256) {
            const int j = e & 7, n = (e >> 3) & 127, g = e >> 10;
            wsWo[e] = f2bs(w_out[(g * 8 + j) * 128 + n]);
        }
    } else if (blk < 12) {
        if (t < 128) {
            const int g = blk - 2, c = t;
            float s = 0.f;
            #pragma unroll
            for (int r = 0; r < 128; ++r) s += w_pos[g * 128 + r] * w_gcm[r * 128 + c];
            wsPG[g * 128 + c] = s;
        }
    } else {
        if (t < 128) {
            const int c = t;
            float sb = b_gcm[c];
            #pragma unroll
            for (int r = 0; r < 128; ++r) sb += b_pos[r] * w_gcm[r * 128 + c];
            wsBeff[c] = sb;
        }
    }
}

// ================= prep B: FW = features @ w_gcm (bf16), 16 rows/block =================
__global__ __launch_bounds__(256) void prep_fw(
    const float* __restrict__ features, const short* __restrict__ wsWpF,
    ushort_t* __restrict__ wsFW)
{
    const int t = threadIdx.x, blk = blockIdx.x;
    __shared__ short sF[16 * SR];
    const int g0 = blk * GRP;
    {   // stage features tile (f32 -> bf16), coalesced
        const int row = t >> 4, c8 = (t & 15) * 8;
        const float* fp = features + (size_t)(g0 + row) * CC + c8;
        const float4 a = *(const float4*)fp;
        const float4 b = *(const float4*)(fp + 4);
        short8 v;
        v[0]=f2bs(a.x); v[1]=f2bs(a.y); v[2]=f2bs(a.z); v[3]=f2bs(a.w);
        v[4]=f2bs(b.x); v[5]=f2bs(b.y); v[6]=f2bs(b.z); v[7]=f2bs(b.w);
        *(short8*)&sF[row * SR + c8] = v;
    }
    const int wv = t >> 6, lane = t & 63, quad = (lane >> 4) & 3, m = lane & 15;
    const int col0 = wv * 32 + m;
    short8 bf[4][2];
    #pragma unroll
    for (int ks = 0; ks < 4; ++ks) {
        bf[ks][0] = *((const short8*)wsWpF + ((ks * 4 + quad) * 128 + col0));
        bf[ks][1] = *((const short8*)wsWpF + ((ks * 4 + quad) * 128 + col0 + 16));
    }
    __syncthreads();
    float4v acc[2] = {};
    #pragma unroll
    for (int ks = 0; ks < 4; ++ks) {
        const short8 a = *(const short8*)(sF + m * SR + ks * 32 + quad * 8);
        acc[0] = MFMA(a, bf[ks][0], acc[0], 0, 0, 0);
        acc[1] = MFMA(a, bf[ks][1], acc[1], 0, 0, 0);
    }
    #pragma unroll
    for (int r = 0; r < 4; ++r) {
        const int R = quad * 4 + r;
        wsFW[(size_t)(g0 + R) * CC + col0]      = (ushort_t)f2bs(acc[0][r]);
        wsFW[(size_t)(g0 + R) * CC + col0 + 16] = (ushort_t)f2bs(acc[1][r]);
    }
}

// ================= main kernel: barrier-free FW-gather + rank-4 geo MFMA =================
// R7-verified schedule (depth-2, 3 buffers, vmcnt 4/2/0), plus:
//   - neighbor indices for the DMA in 16 regs/lane (sIdx deleted: -2KB LDS, no in-loop idx read)
//   - sched_barrier(0x6) after vmcnt: VALU/SALU may cross into the gather-wait shadow
//   - s_setprio(1) around unpack+MFMA cluster (waves fully desynced -> T5 regime)
__global__ __launch_bounds__(256, 4) void bridge_fw(
    const float* __restrict__ points, const float* __restrict__ features,
    const int*   __restrict__ gidx,
    const short* __restrict__ wsWo, const float* __restrict__ wsBeff,
    const float* __restrict__ wsPG, const ushort_t* __restrict__ wsFW,
    const float* __restrict__ b_out, const float* __restrict__ ln_g,
    const float* __restrict__ ln_b, float* __restrict__ out)
{
    __shared__ short sA[4][3][1024];      // [wave][buf] gathered FW tiles (24 KB)
    __shared__ float sGxyz[GRP * KK * 3]; // all neighbor xyz (6 KB)
    __shared__ short sRes[GRP * SR];      // 4.25 KB
    __shared__ float sCtr[GRP * 3];
    __shared__ float sPS[4][GRP], sPQ[4][GRP];

    const int t = threadIdx.x, wv = t >> 6, lane = t & 63;
    const int q = (lane >> 4) & 3, m = lane & 15;
    const int g0 = blockIdx.x * GRP;
    const int nbase = (g0 >= NN) ? NN : 0;
    const int colA = wv * 32 + m;
    const int rbL = lane >> 3, jL = (lane & 7) >> 1, hL = lane & 1;  // DMA lane roles

    // ---- prologue staging (plain loads; drained by the one __syncthreads) ----
    {
        const int gA = gidx[(size_t)g0 * KK + t];
        const int gB = gidx[(size_t)g0 * KK + t + 256];
        const float* pA = points + (size_t)(nbase + gA) * 3;
        const float* pB = points + (size_t)(nbase + gB) * 3;
        sGxyz[t * 3 + 0] = pA[0]; sGxyz[t * 3 + 1] = pA[1]; sGxyz[t * 3 + 2] = pA[2];
        sGxyz[(t + 256) * 3 + 0] = pB[0];
        sGxyz[(t + 256) * 3 + 1] = pB[1];
        sGxyz[(t + 256) * 3 + 2] = pB[2];
    }
    if (t < GRP * 3) sCtr[t] = points[(size_t)g0 * 3 + t];

    // DMA neighbor indices -> registers (static indexing after full unroll, rule #20)
    int kwReg[GRP];
    {
        const int offL = rbL * 4 + jL;
        #pragma unroll
        for (int p = 0; p < GRP; ++p)
            kwReg[p] = nbase + gidx[(size_t)g0 * KK + p * KK + offL];
    }

    // residual features -> registers (f32): lane (q,m) holds points q*4..q*4+3
    float rr[4][2];
    #pragma unroll
    for (int j = 0; j < 4; ++j) {
        const size_t pt = (size_t)(g0 + q * 4 + j) * CC;
        rr[j][0] = features[pt + colA];
        rr[j][1] = features[pt + colA + 16];
    }

    const float beffv[2] = { wsBeff[colA], wsBeff[colA + 16] };
    // per-column geo weights derived from wsPG (L2-hot):
    float wc[6];
    short8 w4f[2];
    #pragma unroll
    for (int n = 0; n < 2; ++n) {
        const int c = colA + n * 16;
        const float p0 = wsPG[0*128+c], p1 = wsPG[1*128+c], p2 = wsPG[2*128+c];
        const float p3 = wsPG[3*128+c], p4 = wsPG[4*128+c], p5 = wsPG[5*128+c];
        const float p6 = wsPG[6*128+c], p7 = wsPG[7*128+c], p8 = wsPG[8*128+c];
        const float p9 = wsPG[9*128+c];
        wc[n*3+0] = p0 - p6; wc[n*3+1] = p1 - p7; wc[n*3+2] = p2 - p8;
        short8 w = (short8)0;
        w[0] = f2bs(p3 + p6); w[1] = f2bs(p4 + p7); w[2] = f2bs(p5 + p8); w[3] = f2bs(p9);
        w4f[n] = (q == 0) ? w : (short8)0;
    }
    // per-lane tr address: base + lane*8 (verified R5)
    const unsigned trBase = (unsigned)(size_t)(__attribute__((address_space(3))) short*)&sA[wv][0][0]
                          + (unsigned)(lane * 8);

    __syncthreads();   // drains ALL prologue vmem; only block-wide barrier before the tail

    auto issue_fw = [&](int p, int buf) {
        // lane (rb, j2, h) fetches row k=rb*4+j2, channels [h*8,h*8+8) (+16ch in GLL1)
        const ushort_t* s0 = wsFW + (size_t)kwReg[p] * CC + wv * 32 + hL * 8;
        GLL(s0,      &sA[wv][buf][0],   16);
        GLL(s0 + 16, &sA[wv][buf][512], 16);
    };

    issue_fw(0, 0);
    issue_fw(1, 1);

    #pragma unroll
    for (int p = 0; p < GRP; ++p) {
        const int buf = p % 3;
        if (p + 2 < GRP) issue_fw(p + 2, (p + 2) % 3);
        // in-loop vmem stream is ONLY the GLLs -> counts exact (2/point, depth-2)
        if (p + 2 < GRP)      asm volatile("s_waitcnt vmcnt(4)" ::: "memory");
        else if (p + 1 < GRP) asm volatile("s_waitcnt vmcnt(2)" ::: "memory");
        else                  asm volatile("s_waitcnt vmcnt(0)" ::: "memory");
        __builtin_amdgcn_sched_barrier(0x6);  // VALU/SALU may fill the gather-wait shadow

        // C fragments: FW[k=q*4+r][colA(+16)] via hardware transpose read
        uint2v t00, t10, t01, t11;
        const unsigned trA = trBase + (unsigned)(buf * 2048);
        asm volatile("ds_read_b64_tr_b16 %0, %1 offset:0"    : "=&v"(t00) : "v"(trA));
        asm volatile("ds_read_b64_tr_b16 %0, %1 offset:512"  : "=&v"(t10) : "v"(trA));
        asm volatile("ds_read_b64_tr_b16 %0, %1 offset:1024" : "=&v"(t01) : "v"(trA));
        asm volatile("ds_read_b64_tr_b16 %0, %1 offset:1536" : "=&v"(t11) : "v"(trA));

        const float pcx = sCtr[p * 3], pcy = sCtr[p * 3 + 1], pcz = sCtr[p * 3 + 2];
        short8 ga0 = (short8)0, ga1 = (short8)0;
        if (q == 0) {   // folded geo A-frag: k-dims {gx, gy, gz, dist}
            const int i0 = (p * KK + m) * 3, i1 = i0 + 48;
            const float ax = sGxyz[i0], ay = sGxyz[i0 + 1], az = sGxyz[i0 + 2];
            const float bx = sGxyz[i1], by = sGxyz[i1 + 1], bz = sGxyz[i1 + 2];
            const float d0x = ax - pcx, d0y = ay - pcy, d0z = az - pcz;
            const float d1x = bx - pcx, d1y = by - pcy, d1z = bz - pcz;
            const float s0 = sqrtf(d0x * d0x + d0y * d0y + d0z * d0z);
            const float s1 = sqrtf(d1x * d1x + d1y * d1y + d1z * d1z);
            ga0[0]=f2bs(ax); ga0[1]=f2bs(ay); ga0[2]=f2bs(az); ga0[3]=f2bs(s0);
            ga1[0]=f2bs(bx); ga1[1]=f2bs(by); ga1[2]=f2bs(bz); ga1[3]=f2bs(s1);
        }

        asm volatile("s_waitcnt lgkmcnt(0)" ::: "memory");   // tr-reads complete
        __builtin_amdgcn_sched_barrier(0);                   // rule #18: pin consumers below

        __builtin_amdgcn_s_setprio(1);
        // unpack gathered FW (bf16 -> f32) as MFMA C-input
        float4v c00, c10, c01, c11;
        c00[0]=__uint_as_float(t00[0] << 16); c00[1]=__uint_as_float(t00[0] & 0xffff0000u);
        c00[2]=__uint_as_float(t00[1] << 16); c00[3]=__uint_as_float(t00[1] & 0xffff0000u);
        c10[0]=__uint_as_float(t10[0] << 16); c10[1]=__uint_as_float(t10[0] & 0xffff0000u);
        c10[2]=__uint_as_float(t10[1] << 16); c10[3]=__uint_as_float(t10[1] & 0xffff0000u);
        c01[0]=__uint_as_float(t01[0] << 16); c01[1]=__uint_as_float(t01[0] & 0xffff0000u);
        c01[2]=__uint_as_float(t01[1] << 16); c01[3]=__uint_as_float(t01[1] & 0xffff0000u);
        c11[0]=__uint_as_float(t11[0] << 16); c11[1]=__uint_as_float(t11[0] & 0xffff0000u);
        c11[2]=__uint_as_float(t11[1] << 16); c11[3]=__uint_as_float(t11[1] & 0xffff0000u);

        c00 = MFMA(ga0, w4f[0], c00, 0, 0, 0);
        c01 = MFMA(ga0, w4f[1], c01, 0, 0, 0);
        c10 = MFMA(ga1, w4f[0], c10, 0, 0, 0);
        c11 = MFMA(ga1, w4f[1], c11, 0, 0, 0);
        __builtin_amdgcn_s_setprio(0);

        const float cb0 = pcx * wc[0] + pcy * wc[1] + pcz * wc[2];
        const float cb1 = pcx * wc[3] + pcy * wc[4] + pcz * wc[5];

        float v0 = fmaxf(fmaxf(fmaxf(c00[0], c00[1]), fmaxf(c00[2], c00[3])),
                         fmaxf(fmaxf(c10[0], c10[1]), fmaxf(c10[2], c10[3])));
        float v1 = fmaxf(fmaxf(fmaxf(c01[0], c01[1]), fmaxf(c01[2], c01[3])),
                         fmaxf(fmaxf(c11[0], c11[1]), fmaxf(c11[2], c11[3])));
        v0 = fmaxf(v0, __shfl_xor(v0, 16)); v0 = fmaxf(v0, __shfl_xor(v0, 32));
        v1 = fmaxf(v1, __shfl_xor(v1, 16)); v1 = fmaxf(v1, __shfl_xor(v1, 32));
        v0 = fmaxf(v0 + beffv[0] + cb0, 0.f);
        v1 = fmaxf(v1 + beffv[1] + cb1, 0.f);

        // residual via register shuffle: holder lane = (p>>2)*16 + m, reg p&3
        const float fc0 = __shfl(rr[p & 3][0], ((p >> 2) << 4) + m);
        const float fc1 = __shfl(rr[p & 3][1], ((p >> 2) << 4) + m);
        if (q == 0) {
            sRes[p * SR + colA]      = f2bs(v0 + fc0);
            sRes[p * SR + colA + 16] = f2bs(v1 + fc1);
        }
    }

    __syncthreads();

    // ---- out projection: res(16x128) @ w_out(128x128) + LN + relu ----
    short8 bWo[4][2];
    #pragma unroll
    for (int ks = 0; ks < 4; ++ks)
        #pragma unroll
        for (int ntl = 0; ntl < 2; ++ntl)
            bWo[ks][ntl] = *((const short8*)wsWo + ((ks * 4 + q) * 128 + colA + ntl * 16));

    const short* rm = sRes + m * SR;
    float4v acc2[2] = {};
    #pragma unroll
    for (int ks = 0; ks < 4; ++ks) {
        const short8 a = *(const short8*)(rm + ks * 32 + q * 8);
        acc2[0] = MFMA(a, bWo[ks][0], acc2[0], 0, 0, 0);
        acc2[1] = MFMA(a, bWo[ks][1], acc2[1], 0, 0, 0);
    }

    const float boutv[2] = { b_out[colA], b_out[colA + 16] };
    const float lngv[2]  = { ln_g[colA], ln_g[colA + 16] };
    const float lnbv[2]  = { ln_b[colA], ln_b[colA + 16] };

    #pragma unroll
    for (int r = 0; r < 4; ++r) {
        const float o0 = acc2[0][r] + boutv[0];
        const float o1 = acc2[1][r] + boutv[1];
        float ss = o0 + o1, qq = o0 * o0 + o1 * o1;
        #pragma unroll
        for (int d = 1; d < 16; d <<= 1) { ss += __shfl_xor(ss, d); qq += __shfl_xor(qq, d); }
        if (m == 0) { sPS[wv][q * 4 + r] = ss; sPQ[wv][q * 4 + r] = qq; }
    }
    __syncthreads();

    #pragma unroll
    for (int r = 0; r < 4; ++r) {
        const int R = q * 4 + r;
        const float S = sPS[0][R] + sPS[1][R] + sPS[2][R] + sPS[3][R];
        const float Q = sPQ[0][R] + sPQ[1][R] + sPQ[2][R] + sPQ[3][R];
        const float mu  = S * (1.f / 128.f);
        const float var = fmaxf(Q * (1.f / 128.f) - mu * mu, 0.f);
        const float rstd = rsqrtf(var + LN_EPS);
        const float o0 = acc2[0][r] + boutv[0];
        const float o1 = acc2[1][r] + boutv[1];
        const size_t base = (size_t)(g0 + R) * CC;
        out[base + colA]      = fmaxf((o0 - mu) * rstd * lngv[0] + lnbv[0], 0.f);
        out[base + colA + 16] = fmaxf((o1 - mu) * rstd * lngv[1] + lnbv[1], 0.f);
    }
}

// ================= fallback path (small workspace; R2-verified structure, f32) =================
__global__ __launch_bounds__(128) void prep_fold_fb(
    const float* __restrict__ w_pos, const float* __restrict__ b_pos,
    const float* __restrict__ w_gcm, const float* __restrict__ b_gcm,
    float* __restrict__ wsPG, float* __restrict__ wsBeff)
{
    const int c = threadIdx.x, g = blockIdx.x;
    if (g < 10) {
        float s = 0.f;
        for (int r = 0; r < 128; ++r) s += w_pos[g * 128 + r] * w_gcm[r * 128 + c];
        wsPG[g * 128 + c] = s;
    } else {
        float s = b_gcm[c];
        for (int r = 0; r < 128; ++r) s += b_pos[r] * w_gcm[r * 128 + c];
        wsBeff[c] = s;
    }
}

__global__ __launch_bounds__(256) void prep_pack_fb(
    const float* __restrict__ w_gcm, const float* __restrict__ w_out,
    const float* __restrict__ wsPG, short* __restrict__ wsWp, short* __restrict__ wsWo)
{
    const int t = threadIdx.x, blk = blockIdx.x;
    if (blk == 0) {
        #pragma unroll 4
        for (int e = t; e < 16 * 128 * 8; e += 256) {
            const int j = e & 7, n = (e >> 3) & 127, g = e >> 10;
            wsWp[e] = f2bs(w_gcm[(g * 8 + j) * 128 + n]);
        }
    } else if (blk == 1) {
        #pragma unroll 4
        for (int e2 = t; e2 < 4 * 128 * 8; e2 += 256) {
            const int e = 16 * 128 * 8 + e2;
            const int j = e & 7, n = (e >> 3) & 127, g = e >> 10;
            const int k = g * 8 + j;
            wsWp[e] = (k < 138) ? f2bs(wsPG[(k - 128) * 128 + n]) : (short)0;
        }
    } else {
        #pragma unroll 4
        for (int e = t; e < 128 * 128; e += 256) {
            const int j = e & 7, n = (e >> 3) & 127, g = e >> 10;
            wsWo[e] = f2bs(w_out[(g * 8 + j) * 128 + n]);
        }
    }
}

__global__ __launch_bounds__(256, 3) void bridge_fb(
    const float* __restrict__ points, const float* __restrict__ features,
    const int*   __restrict__ gidx,
    const short* __restrict__ wsWp, const short* __restrict__ wsWo,
    const float* __restrict__ wsBeff,
    const float* __restrict__ b_out, const float* __restrict__ ln_g,
    const float* __restrict__ ln_b, float* __restrict__ out)
{
    __shared__ short sA[4][KK * CC];
    __shared__ short sG[3][KK * SG2];
    __shared__ short sRes[GRP * SR];
    __shared__ short sResF[GRP * CC];
    __shared__ int   sIdx[GRP * KK];
    __shared__ float sCtr[GRP * 3];
    __shared__ float sPS[4][GRP], sPQ[4][GRP];

    const int t = threadIdx.x, wv = t >> 6, lane = t & 63;
    const int quad = (lane >> 4) & 3, m = lane & 15;
    const int g0 = blockIdx.x * GRP;
    const int nbase = (g0 >= NN) ? NN : 0;
    const int col0 = wv * 32 + m;

    sIdx[t]       = gidx[(size_t)g0 * KK + t];
    sIdx[t + 256] = gidx[(size_t)g0 * KK + t + 256];
    if (t < GRP * 3) sCtr[t] = points[(size_t)g0 * 3 + t];
    {
        const float* fs = features + (size_t)g0 * CC + t * 8;
        short8 v;
        #pragma unroll
        for (int i = 0; i < 8; ++i) v[i] = f2bs(fs[i]);
        *(short8*)&sResF[t * 8] = v;
    }

    short8 bWp[5][2];
    #pragma unroll
    for (int ks = 0; ks < 5; ++ks)
        #pragma unroll
        for (int ntl = 0; ntl < 2; ++ntl)
            bWp[ks][ntl] = *((const short8*)wsWp + ((ks * 4 + quad) * 128 + col0 + ntl * 16));
    const float beffv[2] = { wsBeff[col0], wsBeff[col0 + 16] };

    __syncthreads();

    const int r0 = wv * 4 + (lane >> 4);
    const int pc = lane & 15;
    const int gc = pc ^ r0;

    float geoS[3][3];

    auto geo_load = [&](int qq) {
        if (lane < 8) {
            const int j = wv * 8 + lane;
            const int kng = nbase + sIdx[qq * KK + j];
            const float* pp = points + (size_t)kng * 3;
            const int s = qq % 3;
            geoS[s][0] = pp[0]; geoS[s][1] = pp[1]; geoS[s][2] = pp[2];
        }
    };
    auto stage = [&](int qq) {
        const int buf = qq & 3;
        const int kn0 = nbase + sIdx[qq * KK + r0];
        const int kn1 = nbase + sIdx[qq * KK + r0 + 16];
        const float4* f0 = (const float4*)(features + (size_t)kn0 * CC + gc * 8);
        const float4* f1 = (const float4*)(features + (size_t)kn1 * CC + gc * 8);
        const float4 a = f0[0], b = f0[1], c = f1[0], d = f1[1];
        short8 v;
        v[0]=f2bs(a.x); v[1]=f2bs(a.y); v[2]=f2bs(a.z); v[3]=f2bs(a.w);
        v[4]=f2bs(b.x); v[5]=f2bs(b.y); v[6]=f2bs(b.z); v[7]=f2bs(b.w);
        *(short8*)&sA[buf][r0 * CC + pc * 8] = v;
        v[0]=f2bs(c.x); v[1]=f2bs(c.y); v[2]=f2bs(c.z); v[3]=f2bs(c.w);
        v[4]=f2bs(d.x); v[5]=f2bs(d.y); v[6]=f2bs(d.z); v[7]=f2bs(d.w);
        *(short8*)&sA[buf][(r0 + 16) * CC + pc * 8] = v;
    };
    auto geo_store = [&](int qq) {
        if (lane < 8) {
            const int j = wv * 8 + lane, s = qq % 3, b = qq % 3;
            const float cx = sCtr[qq * 3], cy = sCtr[qq * 3 + 1], cz = sCtr[qq * 3 + 2];
            const float gx = geoS[s][0], gy = geoS[s][1], gz = geoS[s][2];
            const float dx = gx - cx, dy = gy - cy, dz = gz - cz;
            const float dist = sqrtf(dx * dx + dy * dy + dz * dz);
            short8 v0, v1 = (short8)0;
            v0[0]=f2bs(cx); v0[1]=f2bs(cy); v0[2]=f2bs(cz);
            v0[3]=f2bs(gx); v0[4]=f2bs(gy); v0[5]=f2bs(gz);
            v0[6]=f2bs(dx); v0[7]=f2bs(dy);
            v1[0]=f2bs(dz); v1[1]=f2bs(dist);
            *(short8*)&sG[b][j * SG2 + 0] = v0;
            *(short8*)&sG[b][j * SG2 + 8] = v1;
        }
    };

    int offA[4];
    #pragma unroll
    for (int ks = 0; ks < 4; ++ks) offA[ks] = m * CC + (((ks * 4 + quad) ^ m) * 8);
    const int offG = m * SG2 + quad * 8;

    geo_load(0); stage(0);
    geo_load(1); stage(1);
    geo_load(2); stage(2);
    geo_store(0); geo_store(1);
    __syncthreads();

    #pragma unroll
    for (int p = 0; p < GRP; ++p) {
        if (p > 0) {
            asm volatile("s_waitcnt lgkmcnt(0)" ::: "memory");
            __builtin_amdgcn_s_barrier();
        }
        __builtin_amdgcn_sched_barrier(0);
        if (p + 3 < GRP) { geo_load(p + 3); stage(p + 3); }

        const short* ab = sA[p & 3];
        const short* ag = sG[p % 3];
        float4v acc[2][2] = {};
        #pragma unroll
        for (int ks = 0; ks < 4; ++ks) {
            const short8 a0 = *(const short8*)(ab + offA[ks]);
            const short8 a1 = *(const short8*)(ab + offA[ks] + 16 * CC);
            acc[0][0] = MFMA(a0, bWp[ks][0], acc[0][0], 0, 0, 0);
            acc[0][1] = MFMA(a0, bWp[ks][1], acc[0][1], 0, 0, 0);
            acc[1][0] = MFMA(a1, bWp[ks][0], acc[1][0], 0, 0, 0);
            acc[1][1] = MFMA(a1, bWp[ks][1], acc[1][1], 0, 0, 0);
        }
        short8 ga0 = (short8)0, ga1 = (short8)0;
        if (quad < 2) {
            ga0 = *(const short8*)(ag + offG);
            ga1 = *(const short8*)(ag + offG + 16 * SG2);
        }
        acc[0][0] = MFMA(ga0, bWp[4][0], acc[0][0], 0, 0, 0);
        acc[0][1] = MFMA(ga0, bWp[4][1], acc[0][1], 0, 0, 0);
        acc[1][0] = MFMA(ga1, bWp[4][0], acc[1][0], 0, 0, 0);
        acc[1][1] = MFMA(ga1, bWp[4][1], acc[1][1], 0, 0, 0);

        #pragma unroll
        for (int ntl = 0; ntl < 2; ++ntl) {
            float v = acc[0][ntl][0];
            #pragma unroll
            for (int rr2 = 1; rr2 < 4; ++rr2) v = fmaxf(v, acc[0][ntl][rr2]);
            #pragma unroll
            for (int rr2 = 0; rr2 < 4; ++rr2) v = fmaxf(v, acc[1][ntl][rr2]);
            v = fmaxf(v, __shfl_xor(v, 16));
            v = fmaxf(v, __shfl_xor(v, 32));
            v = fmaxf(v + beffv[ntl], 0.f);
            if (quad == 0) {
                const float fc = bs2f((ushort_t)sResF[p * CC + col0 + ntl * 16]);
                sRes[p * SR + col0 + ntl * 16] = f2bs(v + fc);
            }
        }
        if (p + 2 < GRP) geo_store(p + 2);
    }

    __syncthreads();

    short8 bWo[4][2];
    #pragma unroll
    for (int ks = 0; ks < 4; ++ks)
        #pragma unroll
        for (int ntl = 0; ntl < 2; ++ntl)
            bWo[ks][ntl] = *((const short8*)wsWo + ((ks * 4 + quad) * 128 + col0 + ntl * 16));

    const short* rm = sRes + m * SR;
    float4v acc2[2] = {};
    #pragma unroll
    for (int ks = 0; ks < 4; ++ks) {
        const short8 a = *(const short8*)(rm + ks * 32 + quad * 8);
        acc2[0] = MFMA(a, bWo[ks][0], acc2[0], 0, 0, 0);
        acc2[1] = MFMA(a, bWo[ks][1], acc2[1], 0, 0, 0);
    }
    const float boutv[2] = { b_out[col0], b_out[col0 + 16] };
    const float lngv[2]  = { ln_g[col0], ln_g[col0 + 16] };
    const float lnbv[2]  = { ln_b[col0], ln_b[col0 + 16] };
    #pragma unroll
    for (int r = 0; r < 4; ++r) {
        const float o0 = acc2[0][r] + boutv[0];
        const float o1 = acc2[1][r] + boutv[1];
        float ss = o0 + o1, qq2 = o0 * o0 + o1 * o1;
        #pragma unroll
        for (int d = 1; d < 16; d <<= 1) { ss += __shfl_xor(ss, d); qq2 += __shfl_xor(qq2, d); }
        if (m == 0) { sPS[wv][quad * 4 + r] = ss; sPQ[wv][quad * 4 + r] = qq2; }
    }
    __syncthreads();
    #pragma unroll
    for (int r = 0; r < 4; ++r) {
        const int R = quad * 4 + r;
        const float S = sPS[0][R] + sPS[1][R] + sPS[2][R] + sPS[3][R];
        const float Q = sPQ[0][R] + sPQ[1][R] + sPQ[2][R] + sPQ[3][R];
        const float mu  = S * (1.f / 128.f);
        const float var = fmaxf(Q * (1.f / 128.f) - mu * mu, 0.f);
        const float rstd = rsqrtf(var + LN_EPS);
        const float o0 = acc2[0][r] + boutv[0];
        const float o1 = acc2[1][r] + boutv[1];
        const size_t base = (size_t)(g0 + R) * CC;
        out[base + col0]      = fmaxf((o0 - mu) * rstd * lngv[0] + lnbv[0], 0.f);
        out[base + col0 + 16] = fmaxf((o1 - mu) * rstd * lngv[1] + lnbv[1], 0.f);
    }
}

extern "C" void kernel_launch(void* const* d_in, const int* in_sizes, int n_in,
                              void* d_out, int out_size, void* d_ws, size_t ws_size,
                              hipStream_t stream) {
    const float* points   = (const float*)d_in[0];
    const float* features = (const float*)d_in[1];
    const int*   gidx     = (const int*)  d_in[2];
    const float* w_pos    = (const float*)d_in[3];
    const float* b_pos    = (const float*)d_in[4];
    const float* w_gcm    = (const float*)d_in[5];
    const float* b_gcm    = (const float*)d_in[6];
    const float* w_out    = (const float*)d_in[7];
    const float* b_out    = (const float*)d_in[8];
    const float* ln_g     = (const float*)d_in[9];
    const float* ln_b     = (const float*)d_in[10];
    float* out = (float*)d_out;
    char* ws = (char*)d_ws;

    if (ws_size >= WS_NEED) {
        ushort_t* wsFW   = (ushort_t*)(ws + WS_FW);
        short*    wsWo   = (short*)(ws + WS_WO);
        float*    wsBeff = (float*)(ws + WS_BE);
        short*    wsWpF  = (short*)(ws + WS_WPF);
        float*    wsPG   = (float*)(ws + WS_PG);
        hipLaunchKernelGGL(prep1, dim3(13), dim3(256), 0, stream,
                           w_gcm, w_out, w_pos, b_pos, b_gcm,
                           wsWpF, wsWo, wsBeff, wsPG);
        hipLaunchKernelGGL(prep_fw, dim3(NPTS / GRP), dim3(256), 0, stream,
                           features, wsWpF, wsFW);
        hipLaunchKernelGGL(bridge_fw, dim3(NPTS / GRP), dim3(256), 0, stream,
                           points, features, gidx, wsWo, wsBeff, wsPG, wsFW,
                           b_out, ln_g, ln_b, out);
    } else {
        short* wsWp   = (short*)(ws + FB_WP);
        short* wsWo   = (short*)(ws + FB_WO);
        float* wsBeff = (float*)(ws + FB_BE);
        float* wsPG   = (float*)(ws + FB_PG);
        hipLaunchKernelGGL(prep_fold_fb, dim3(11), dim3(128), 0, stream,
                           w_pos, b_pos, w_gcm, b_gcm, wsPG, wsBeff);
        hipLaunchKernelGGL(prep_pack_fb, dim3(3), dim3(256), 0, stream,
                           w_gcm, w_out, wsPG, wsWp, wsWo);
        hipLaunchKernelGGL(bridge_fb, dim3(NPTS / GRP), dim3(256), 0, stream,
                           points, features, gidx, wsWp, wsWo, wsBeff,
                           b_out, ln_g, ln_b, out);
    }
}

// Round 9
// 140.644 us; speedup vs baseline: 1.2032x; 1.0086x over previous
//
#include <hip/hip_runtime.h>
#include <hip/hip_bf16.h>
#include <math.h>

typedef __attribute__((ext_vector_type(8))) short short8;
typedef __attribute__((ext_vector_type(4))) short short4v;
typedef __attribute__((ext_vector_type(4))) float float4v;
typedef __attribute__((ext_vector_type(2))) unsigned int uint2v;
typedef unsigned short ushort_t;

constexpr int NPTS = 32768;  // B*N
constexpr int NN   = 16384;  // points per batch
constexpr int KK   = 32;     // neighbors
constexpr int CC   = 128;    // channels
constexpr int GRP  = 16;     // points per block -> grid 2048
constexpr int SR   = 136;    // res LDS row stride (shorts)
constexpr int SG2  = 24;     // fallback geo stride
#define LN_EPS 1e-5f
#define MFMA   __builtin_amdgcn_mfma_f32_16x16x32_bf16
#define GLL(src, dst, sz) __builtin_amdgcn_global_load_lds( \
    (const __attribute__((address_space(1))) void*)(src),   \
    (__attribute__((address_space(3))) void*)(dst), sz, 0, 0)

// ---- new-path workspace layout ----
constexpr size_t WS_FW  = 0;                       // FW bf16: 32768*128*2 = 8388608
constexpr size_t WS_WO  = (size_t)NPTS * CC * 2;   // w_out frag-packed: 32768 B
constexpr size_t WS_BE  = WS_WO + 32768;           // beff: 512 B
constexpr size_t WS_WPF = WS_BE + 512;             // w_gcm frag-packed: 32768 B
constexpr size_t WS_PG  = WS_WPF + 32768;          // PG = w_pos@w_gcm: 10*128 f32 = 5120 B
constexpr size_t WS_NEED = WS_PG + 5120;           // 8459776 (known available)
// ---- fallback workspace layout (old scheme, small) ----
constexpr size_t FB_WP = 0, FB_WO = 40960, FB_BE = 73728, FB_PG = 74240;

__device__ __forceinline__ short f2bs(float x) {
    return (short)__builtin_bit_cast(unsigned short, __float2bfloat16(x));
}
__device__ __forceinline__ float bs2f(ushort_t u) {
    return __uint_as_float(((unsigned)u) << 16);
}

// ================= prep1: all weight packs, 13 independent blocks =================
__global__ __launch_bounds__(256) void prep1(
    const float* __restrict__ w_gcm, const float* __restrict__ w_out,
    const float* __restrict__ w_pos, const float* __restrict__ b_pos,
    const float* __restrict__ b_gcm,
    short* __restrict__ wsWpF, short* __restrict__ wsWo,
    float* __restrict__ wsBeff, float* __restrict__ wsPG)
{
    const int t = threadIdx.x, blk = blockIdx.x;
    if (blk == 0) {
        #pragma unroll 4
        for (int e = t; e < 16 * 128 * 8; e += 256) {
            const int j = e & 7, n = (e >> 3) & 127, g = e >> 10;
            wsWpF[e] = f2bs(w_gcm[(g * 8 + j) * 128 + n]);
        }
    } else if (blk == 1) {
        #pragma unroll 4
        for (int e = t; e < 128 * 128; e += 256) {
            const int j = e & 7, n = (e >> 3) & 127, g = e >> 10;
            wsWo[e] = f2bs(w_out[(g * 8 + j) * 128 + n]);
        }
    } else if (blk < 12) {
        if (t < 128) {
            const int g = blk - 2, c = t;
            float s = 0.f;
            #pragma unroll
            for (int r = 0; r < 128; ++r) s += w_pos[g * 128 + r] * w_gcm[r * 128 + c];
            wsPG[g * 128 + c] = s;
        }
    } else {
        if (t < 128) {
            const int c = t;
            float sb = b_gcm[c];
            #pragma unroll
            for (int r = 0; r < 128; ++r) sb += b_pos[r] * w_gcm[r * 128 + c];
            wsBeff[c] = sb;
        }
    }
}

// ================= prep B: FW = features @ w_gcm (bf16), 16 rows/block =================
__global__ __launch_bounds__(256) void prep_fw(
    const float* __restrict__ features, const short* __restrict__ wsWpF,
    ushort_t* __restrict__ wsFW)
{
    const int t = threadIdx.x, blk = blockIdx.x;
    __shared__ short sF[16 * SR];
    const int g0 = blk * GRP;
    {   // stage features tile (f32 -> bf16), coalesced
        const int row = t >> 4, c8 = (t & 15) * 8;
        const float* fp = features + (size_t)(g0 + row) * CC + c8;
        const float4 a = *(const float4*)fp;
        const float4 b = *(const float4*)(fp + 4);
        short8 v;
        v[0]=f2bs(a.x); v[1]=f2bs(a.y); v[2]=f2bs(a.z); v[3]=f2bs(a.w);
        v[4]=f2bs(b.x); v[5]=f2bs(b.y); v[6]=f2bs(b.z); v[7]=f2bs(b.w);
        *(short8*)&sF[row * SR + c8] = v;
    }
    const int wv = t >> 6, lane = t & 63, quad = (lane >> 4) & 3, m = lane & 15;
    const int col0 = wv * 32 + m;
    short8 bf[4][2];
    #pragma unroll
    for (int ks = 0; ks < 4; ++ks) {
        bf[ks][0] = *((const short8*)wsWpF + ((ks * 4 + quad) * 128 + col0));
        bf[ks][1] = *((const short8*)wsWpF + ((ks * 4 + quad) * 128 + col0 + 16));
    }
    __syncthreads();
    float4v acc[2] = {};
    #pragma unroll
    for (int ks = 0; ks < 4; ++ks) {
        const short8 a = *(const short8*)(sF + m * SR + ks * 32 + quad * 8);
        acc[0] = MFMA(a, bf[ks][0], acc[0], 0, 0, 0);
        acc[1] = MFMA(a, bf[ks][1], acc[1], 0, 0, 0);
    }
    #pragma unroll
    for (int r = 0; r < 4; ++r) {
        const int R = quad * 4 + r;
        wsFW[(size_t)(g0 + R) * CC + col0]      = (ushort_t)f2bs(acc[0][r]);
        wsFW[(size_t)(g0 + R) * CC + col0 + 16] = (ushort_t)f2bs(acc[1][r]);
    }
}

// ================= main kernel: barrier-free FW-gather + rank-4 geo MFMA =================
// R8-verified schedule (depth-2, 3 buffers, vmcnt 4/2/0, tr-reads, setprio, 0x6 shadow),
// plus hoisting of ALL point-invariant VALU out of the loop:
//   - geo A-fragments {gx,gy,gz,dist} precomputed for all 512 (p,row) pairs in the
//     prologue (block-wide, 2/thread) into sGeo (4 KB) -> in-loop geo = 2x ds_read_b64
//   - center-bias cbv[16][2] precomputed into regs -> no in-loop sCtr reads / FMAs
__global__ __launch_bounds__(256, 4) void bridge_fw(
    const float* __restrict__ points, const float* __restrict__ features,
    const int*   __restrict__ gidx,
    const short* __restrict__ wsWo, const float* __restrict__ wsBeff,
    const float* __restrict__ wsPG, const ushort_t* __restrict__ wsFW,
    const float* __restrict__ b_out, const float* __restrict__ ln_g,
    const float* __restrict__ ln_b, float* __restrict__ out)
{
    __shared__ short sA[4][3][1024];      // [wave][buf] gathered FW tiles (24 KB)
    __shared__ short sGeo[GRP * KK * 4];  // geo frags {gx,gy,gz,dist} bf16 (4 KB)
    __shared__ short sRes[GRP * SR];      // 4.25 KB
    __shared__ float sCtr[GRP * 3];
    __shared__ float sPS[4][GRP], sPQ[4][GRP];

    const int t = threadIdx.x, wv = t >> 6, lane = t & 63;
    const int q = (lane >> 4) & 3, m = lane & 15;
    const int g0 = blockIdx.x * GRP;
    const int nbase = (g0 >= NN) ? NN : 0;
    const int colA = wv * 32 + m;
    const int rbL = lane >> 3, jL = (lane & 7) >> 1, hL = lane & 1;  // DMA lane roles

    // ---- prologue: geo fragments for all (p,row) pairs, 2 per thread ----
    #pragma unroll
    for (int rep = 0; rep < 2; ++rep) {
        const int e = t + rep * 256;          // e = p*32 + j
        const int p = e >> 5;
        const int gA = gidx[(size_t)g0 * KK + e];
        const float* pn = points + (size_t)(nbase + gA) * 3;
        const float* pcp = points + (size_t)(g0 + p) * 3;
        const float ax = pn[0], ay = pn[1], az = pn[2];
        const float dx = ax - pcp[0], dy = ay - pcp[1], dz = az - pcp[2];
        const float ds = sqrtf(dx * dx + dy * dy + dz * dz);
        short4v v; v[0]=f2bs(ax); v[1]=f2bs(ay); v[2]=f2bs(az); v[3]=f2bs(ds);
        *(short4v*)&sGeo[e * 4] = v;
    }
    if (t < GRP * 3) sCtr[t] = points[(size_t)g0 * 3 + t];

    // DMA neighbor indices -> registers (static indexing after full unroll, rule #20)
    int kwReg[GRP];
    {
        const int offL = rbL * 4 + jL;
        #pragma unroll
        for (int p = 0; p < GRP; ++p)
            kwReg[p] = nbase + gidx[(size_t)g0 * KK + p * KK + offL];
    }

    // residual features -> registers (f32): lane (q,m) holds points q*4..q*4+3
    float rr[4][2];
    #pragma unroll
    for (int j = 0; j < 4; ++j) {
        const size_t pt = (size_t)(g0 + q * 4 + j) * CC;
        rr[j][0] = features[pt + colA];
        rr[j][1] = features[pt + colA + 16];
    }

    const float beffv[2] = { wsBeff[colA], wsBeff[colA + 16] };
    // per-column geo weights derived from wsPG (L2-hot):
    float wc[6];
    short8 w4f[2];
    #pragma unroll
    for (int n = 0; n < 2; ++n) {
        const int c = colA + n * 16;
        const float p0 = wsPG[0*128+c], p1 = wsPG[1*128+c], p2 = wsPG[2*128+c];
        const float p3 = wsPG[3*128+c], p4 = wsPG[4*128+c], p5 = wsPG[5*128+c];
        const float p6 = wsPG[6*128+c], p7 = wsPG[7*128+c], p8 = wsPG[8*128+c];
        const float p9 = wsPG[9*128+c];
        wc[n*3+0] = p0 - p6; wc[n*3+1] = p1 - p7; wc[n*3+2] = p2 - p8;
        short8 w = (short8)0;
        w[0] = f2bs(p3 + p6); w[1] = f2bs(p4 + p7); w[2] = f2bs(p5 + p8); w[3] = f2bs(p9);
        w4f[n] = (q == 0) ? w : (short8)0;
    }
    // per-lane tr address: base + lane*8 (verified R5)
    const unsigned trBase = (unsigned)(size_t)(__attribute__((address_space(3))) short*)&sA[wv][0][0]
                          + (unsigned)(lane * 8);

    __syncthreads();   // drains ALL prologue vmem+lds; only block-wide barrier before the tail

    auto issue_fw = [&](int p, int buf) {
        // lane (rb, j2, h) fetches row k=rb*4+j2, channels [h*8,h*8+8) (+16ch in GLL1)
        const ushort_t* s0 = wsFW + (size_t)kwReg[p] * CC + wv * 32 + hL * 8;
        GLL(s0,      &sA[wv][buf][0],   16);
        GLL(s0 + 16, &sA[wv][buf][512], 16);
    };

    issue_fw(0, 0);
    issue_fw(1, 1);

    // center-bias per point per column (after barrier, fills GLL latency)
    float cbv[GRP][2];
    #pragma unroll
    for (int p = 0; p < GRP; ++p) {
        const float cx = sCtr[p * 3], cy = sCtr[p * 3 + 1], cz = sCtr[p * 3 + 2];
        cbv[p][0] = cx * wc[0] + cy * wc[1] + cz * wc[2];
        cbv[p][1] = cx * wc[3] + cy * wc[4] + cz * wc[5];
    }

    #pragma unroll
    for (int p = 0; p < GRP; ++p) {
        const int buf = p % 3;
        if (p + 2 < GRP) issue_fw(p + 2, (p + 2) % 3);
        // in-loop vmem stream is ONLY the GLLs -> counts exact (2/point, depth-2)
        if (p + 2 < GRP)      asm volatile("s_waitcnt vmcnt(4)" ::: "memory");
        else if (p + 1 < GRP) asm volatile("s_waitcnt vmcnt(2)" ::: "memory");
        else                  asm volatile("s_waitcnt vmcnt(0)" ::: "memory");
        __builtin_amdgcn_sched_barrier(0x6);  // VALU/SALU may fill the gather-wait shadow

        // C fragments: FW[k=q*4+r][colA(+16)] via hardware transpose read
        uint2v t00, t10, t01, t11;
        const unsigned trA = trBase + (unsigned)(buf * 2048);
        asm volatile("ds_read_b64_tr_b16 %0, %1 offset:0"    : "=&v"(t00) : "v"(trA));
        asm volatile("ds_read_b64_tr_b16 %0, %1 offset:512"  : "=&v"(t10) : "v"(trA));
        asm volatile("ds_read_b64_tr_b16 %0, %1 offset:1024" : "=&v"(t01) : "v"(trA));
        asm volatile("ds_read_b64_tr_b16 %0, %1 offset:1536" : "=&v"(t11) : "v"(trA));

        // geo A-frags: precomputed, 8 B LDS reads (q==0 lanes only)
        short8 ga0 = (short8)0, ga1 = (short8)0;
        if (q == 0) {
            const short4v gA0 = *(const short4v*)&sGeo[(p * KK + m) * 4];
            const short4v gA1 = *(const short4v*)&sGeo[(p * KK + 16 + m) * 4];
            ga0[0]=gA0[0]; ga0[1]=gA0[1]; ga0[2]=gA0[2]; ga0[3]=gA0[3];
            ga1[0]=gA1[0]; ga1[1]=gA1[1]; ga1[2]=gA1[2]; ga1[3]=gA1[3];
        }

        asm volatile("s_waitcnt lgkmcnt(0)" ::: "memory");   // tr-reads + geo reads complete
        __builtin_amdgcn_sched_barrier(0);                   // rule #18: pin consumers below

        __builtin_amdgcn_s_setprio(1);
        // unpack gathered FW (bf16 -> f32) as MFMA C-input
        float4v c00, c10, c01, c11;
        c00[0]=__uint_as_float(t00[0] << 16); c00[1]=__uint_as_float(t00[0] & 0xffff0000u);
        c00[2]=__uint_as_float(t00[1] << 16); c00[3]=__uint_as_float(t00[1] & 0xffff0000u);
        c10[0]=__uint_as_float(t10[0] << 16); c10[1]=__uint_as_float(t10[0] & 0xffff0000u);
        c10[2]=__uint_as_float(t10[1] << 16); c10[3]=__uint_as_float(t10[1] & 0xffff0000u);
        c01[0]=__uint_as_float(t01[0] << 16); c01[1]=__uint_as_float(t01[0] & 0xffff0000u);
        c01[2]=__uint_as_float(t01[1] << 16); c01[3]=__uint_as_float(t01[1] & 0xffff0000u);
        c11[0]=__uint_as_float(t11[0] << 16); c11[1]=__uint_as_float(t11[0] & 0xffff0000u);
        c11[2]=__uint_as_float(t11[1] << 16); c11[3]=__uint_as_float(t11[1] & 0xffff0000u);

        c00 = MFMA(ga0, w4f[0], c00, 0, 0, 0);
        c01 = MFMA(ga0, w4f[1], c01, 0, 0, 0);
        c10 = MFMA(ga1, w4f[0], c10, 0, 0, 0);
        c11 = MFMA(ga1, w4f[1], c11, 0, 0, 0);
        __builtin_amdgcn_s_setprio(0);

        float v0 = fmaxf(fmaxf(fmaxf(c00[0], c00[1]), fmaxf(c00[2], c00[3])),
                         fmaxf(fmaxf(c10[0], c10[1]), fmaxf(c10[2], c10[3])));
        float v1 = fmaxf(fmaxf(fmaxf(c01[0], c01[1]), fmaxf(c01[2], c01[3])),
                         fmaxf(fmaxf(c11[0], c11[1]), fmaxf(c11[2], c11[3])));
        v0 = fmaxf(v0, __shfl_xor(v0, 16)); v0 = fmaxf(v0, __shfl_xor(v0, 32));
        v1 = fmaxf(v1, __shfl_xor(v1, 16)); v1 = fmaxf(v1, __shfl_xor(v1, 32));
        v0 = fmaxf(v0 + beffv[0] + cbv[p][0], 0.f);
        v1 = fmaxf(v1 + beffv[1] + cbv[p][1], 0.f);

        // residual via register shuffle: holder lane = (p>>2)*16 + m, reg p&3
        const float fc0 = __shfl(rr[p & 3][0], ((p >> 2) << 4) + m);
        const float fc1 = __shfl(rr[p & 3][1], ((p >> 2) << 4) + m);
        if (q == 0) {
            sRes[p * SR + colA]      = f2bs(v0 + fc0);
            sRes[p * SR + colA + 16] = f2bs(v1 + fc1);
        }
    }

    __syncthreads();

    // ---- out projection: res(16x128) @ w_out(128x128) + LN + relu ----
    short8 bWo[4][2];
    #pragma unroll
    for (int ks = 0; ks < 4; ++ks)
        #pragma unroll
        for (int ntl = 0; ntl < 2; ++ntl)
            bWo[ks][ntl] = *((const short8*)wsWo + ((ks * 4 + q) * 128 + colA + ntl * 16));

    const short* rm = sRes + m * SR;
    float4v acc2[2] = {};
    #pragma unroll
    for (int ks = 0; ks < 4; ++ks) {
        const short8 a = *(const short8*)(rm + ks * 32 + q * 8);
        acc2[0] = MFMA(a, bWo[ks][0], acc2[0], 0, 0, 0);
        acc2[1] = MFMA(a, bWo[ks][1], acc2[1], 0, 0, 0);
    }

    const float boutv[2] = { b_out[colA], b_out[colA + 16] };
    const float lngv[2]  = { ln_g[colA], ln_g[colA + 16] };
    const float lnbv[2]  = { ln_b[colA], ln_b[colA + 16] };

    #pragma unroll
    for (int r = 0; r < 4; ++r) {
        const float o0 = acc2[0][r] + boutv[0];
        const float o1 = acc2[1][r] + boutv[1];
        float ss = o0 + o1, qq = o0 * o0 + o1 * o1;
        #pragma unroll
        for (int d = 1; d < 16; d <<= 1) { ss += __shfl_xor(ss, d); qq += __shfl_xor(qq, d); }
        if (m == 0) { sPS[wv][q * 4 + r] = ss; sPQ[wv][q * 4 + r] = qq; }
    }
    __syncthreads();

    #pragma unroll
    for (int r = 0; r < 4; ++r) {
        const int R = q * 4 + r;
        const float S = sPS[0][R] + sPS[1][R] + sPS[2][R] + sPS[3][R];
        const float Q = sPQ[0][R] + sPQ[1][R] + sPQ[2][R] + sPQ[3][R];
        const float mu  = S * (1.f / 128.f);
        const float var = fmaxf(Q * (1.f / 128.f) - mu * mu, 0.f);
        const float rstd = rsqrtf(var + LN_EPS);
        const float o0 = acc2[0][r] + boutv[0];
        const float o1 = acc2[1][r] + boutv[1];
        const size_t base = (size_t)(g0 + R) * CC;
        out[base + colA]      = fmaxf((o0 - mu) * rstd * lngv[0] + lnbv[0], 0.f);
        out[base + colA + 16] = fmaxf((o1 - mu) * rstd * lngv[1] + lnbv[1], 0.f);
    }
}

// ================= fallback path (small workspace; R2-verified structure, f32) =================
__global__ __launch_bounds__(128) void prep_fold_fb(
    const float* __restrict__ w_pos, const float* __restrict__ b_pos,
    const float* __restrict__ w_gcm, const float* __restrict__ b_gcm,
    float* __restrict__ wsPG, float* __restrict__ wsBeff)
{
    const int c = threadIdx.x, g = blockIdx.x;
    if (g < 10) {
        float s = 0.f;
        for (int r = 0; r < 128; ++r) s += w_pos[g * 128 + r] * w_gcm[r * 128 + c];
        wsPG[g * 128 + c] = s;
    } else {
        float s = b_gcm[c];
        for (int r = 0; r < 128; ++r) s += b_pos[r] * w_gcm[r * 128 + c];
        wsBeff[c] = s;
    }
}

__global__ __launch_bounds__(256) void prep_pack_fb(
    const float* __restrict__ w_gcm, const float* __restrict__ w_out,
    const float* __restrict__ wsPG, short* __restrict__ wsWp, short* __restrict__ wsWo)
{
    const int t = threadIdx.x, blk = blockIdx.x;
    if (blk == 0) {
        #pragma unroll 4
        for (int e = t; e < 16 * 128 * 8; e += 256) {
            const int j = e & 7, n = (e >> 3) & 127, g = e >> 10;
            wsWp[e] = f2bs(w_gcm[(g * 8 + j) * 128 + n]);
        }
    } else if (blk == 1) {
        #pragma unroll 4
        for (int e2 = t; e2 < 4 * 128 * 8; e2 += 256) {
            const int e = 16 * 128 * 8 + e2;
            const int j = e & 7, n = (e >> 3) & 127, g = e >> 10;
            const int k = g * 8 + j;
            wsWp[e] = (k < 138) ? f2bs(wsPG[(k - 128) * 128 + n]) : (short)0;
        }
    } else {
        #pragma unroll 4
        for (int e = t; e < 128 * 128; e += 256) {
            const int j = e & 7, n = (e >> 3) & 127, g = e >> 10;
            wsWo[e] = f2bs(w_out[(g * 8 + j) * 128 + n]);
        }
    }
}

__global__ __launch_bounds__(256, 3) void bridge_fb(
    const float* __restrict__ points, const float* __restrict__ features,
    const int*   __restrict__ gidx,
    const short* __restrict__ wsWp, const short* __restrict__ wsWo,
    const float* __restrict__ wsBeff,
    const float* __restrict__ b_out, const float* __restrict__ ln_g,
    const float* __restrict__ ln_b, float* __restrict__ out)
{
    __shared__ short sA[4][KK * CC];
    __shared__ short sG[3][KK * SG2];
    __shared__ short sRes[GRP * SR];
    __shared__ short sResF[GRP * CC];
    __shared__ int   sIdx[GRP * KK];
    __shared__ float sCtr[GRP * 3];
    __shared__ float sPS[4][GRP], sPQ[4][GRP];

    const int t = threadIdx.x, wv = t >> 6, lane = t & 63;
    const int quad = (lane >> 4) & 3, m = lane & 15;
    const int g0 = blockIdx.x * GRP;
    const int nbase = (g0 >= NN) ? NN : 0;
    const int col0 = wv * 32 + m;

    sIdx[t]       = gidx[(size_t)g0 * KK + t];
    sIdx[t + 256] = gidx[(size_t)g0 * KK + t + 256];
    if (t < GRP * 3) sCtr[t] = points[(size_t)g0 * 3 + t];
    {
        const float* fs = features + (size_t)g0 * CC + t * 8;
        short8 v;
        #pragma unroll
        for (int i = 0; i < 8; ++i) v[i] = f2bs(fs[i]);
        *(short8*)&sResF[t * 8] = v;
    }

    short8 bWp[5][2];
    #pragma unroll
    for (int ks = 0; ks < 5; ++ks)
        #pragma unroll
        for (int ntl = 0; ntl < 2; ++ntl)
            bWp[ks][ntl] = *((const short8*)wsWp + ((ks * 4 + quad) * 128 + col0 + ntl * 16));
    const float beffv[2] = { wsBeff[col0], wsBeff[col0 + 16] };

    __syncthreads();

    const int r0 = wv * 4 + (lane >> 4);
    const int pc = lane & 15;
    const int gc = pc ^ r0;

    float geoS[3][3];

    auto geo_load = [&](int qq) {
        if (lane < 8) {
            const int j = wv * 8 + lane;
            const int kng = nbase + sIdx[qq * KK + j];
            const float* pp = points + (size_t)kng * 3;
            const int s = qq % 3;
            geoS[s][0] = pp[0]; geoS[s][1] = pp[1]; geoS[s][2] = pp[2];
        }
    };
    auto stage = [&](int qq) {
        const int buf = qq & 3;
        const int kn0 = nbase + sIdx[qq * KK + r0];
        const int kn1 = nbase + sIdx[qq * KK + r0 + 16];
        const float4* f0 = (const float4*)(features + (size_t)kn0 * CC + gc * 8);
        const float4* f1 = (const float4*)(features + (size_t)kn1 * CC + gc * 8);
        const float4 a = f0[0], b = f0[1], c = f1[0], d = f1[1];
        short8 v;
        v[0]=f2bs(a.x); v[1]=f2bs(a.y); v[2]=f2bs(a.z); v[3]=f2bs(a.w);
        v[4]=f2bs(b.x); v[5]=f2bs(b.y); v[6]=f2bs(b.z); v[7]=f2bs(b.w);
        *(short8*)&sA[buf][r0 * CC + pc * 8] = v;
        v[0]=f2bs(c.x); v[1]=f2bs(c.y); v[2]=f2bs(c.z); v[3]=f2bs(c.w);
        v[4]=f2bs(d.x); v[5]=f2bs(d.y); v[6]=f2bs(d.z); v[7]=f2bs(d.w);
        *(short8*)&sA[buf][(r0 + 16) * CC + pc * 8] = v;
    };
    auto geo_store = [&](int qq) {
        if (lane < 8) {
            const int j = wv * 8 + lane, s = qq % 3, b = qq % 3;
            const float cx = sCtr[qq * 3], cy = sCtr[qq * 3 + 1], cz = sCtr[qq * 3 + 2];
            const float gx = geoS[s][0], gy = geoS[s][1], gz = geoS[s][2];
            const float dx = gx - cx, dy = gy - cy, dz = gz - cz;
            const float dist = sqrtf(dx * dx + dy * dy + dz * dz);
            short8 v0, v1 = (short8)0;
            v0[0]=f2bs(cx); v0[1]=f2bs(cy); v0[2]=f2bs(cz);
            v0[3]=f2bs(gx); v0[4]=f2bs(gy); v0[5]=f2bs(gz);
            v0[6]=f2bs(dx); v0[7]=f2bs(dy);
            v1[0]=f2bs(dz); v1[1]=f2bs(dist);
            *(short8*)&sG[b][j * SG2 + 0] = v0;
            *(short8*)&sG[b][j * SG2 + 8] = v1;
        }
    };

    int offA[4];
    #pragma unroll
    for (int ks = 0; ks < 4; ++ks) offA[ks] = m * CC + (((ks * 4 + quad) ^ m) * 8);
    const int offG = m * SG2 + quad * 8;

    geo_load(0); stage(0);
    geo_load(1); stage(1);
    geo_load(2); stage(2);
    geo_store(0); geo_store(1);
    __syncthreads();

    #pragma unroll
    for (int p = 0; p < GRP; ++p) {
        if (p > 0) {
            asm volatile("s_waitcnt lgkmcnt(0)" ::: "memory");
            __builtin_amdgcn_s_barrier();
        }
        __builtin_amdgcn_sched_barrier(0);
        if (p + 3 < GRP) { geo_load(p + 3); stage(p + 3); }

        const short* ab = sA[p & 3];
        const short* ag = sG[p % 3];
        float4v acc[2][2] = {};
        #pragma unroll
        for (int ks = 0; ks < 4; ++ks) {
            const short8 a0 = *(const short8*)(ab + offA[ks]);
            const short8 a1 = *(const short8*)(ab + offA[ks] + 16 * CC);
            acc[0][0] = MFMA(a0, bWp[ks][0], acc[0][0], 0, 0, 0);
            acc[0][1] = MFMA(a0, bWp[ks][1], acc[0][1], 0, 0, 0);
            acc[1][0] = MFMA(a1, bWp[ks][0], acc[1][0], 0, 0, 0);
            acc[1][1] = MFMA(a1, bWp[ks][1], acc[1][1], 0, 0, 0);
        }
        short8 ga0 = (short8)0, ga1 = (short8)0;
        if (quad < 2) {
            ga0 = *(const short8*)(ag + offG);
            ga1 = *(const short8*)(ag + offG + 16 * SG2);
        }
        acc[0][0] = MFMA(ga0, bWp[4][0], acc[0][0], 0, 0, 0);
        acc[0][1] = MFMA(ga0, bWp[4][1], acc[0][1], 0, 0, 0);
        acc[1][0] = MFMA(ga1, bWp[4][0], acc[1][0], 0, 0, 0);
        acc[1][1] = MFMA(ga1, bWp[4][1], acc[1][1], 0, 0, 0);

        #pragma unroll
        for (int ntl = 0; ntl < 2; ++ntl) {
            float v = acc[0][ntl][0];
            #pragma unroll
            for (int rr2 = 1; rr2 < 4; ++rr2) v = fmaxf(v, acc[0][ntl][rr2]);
            #pragma unroll
            for (int rr2 = 0; rr2 < 4; ++rr2) v = fmaxf(v, acc[1][ntl][rr2]);
            v = fmaxf(v, __shfl_xor(v, 16));
            v = fmaxf(v, __shfl_xor(v, 32));
            v = fmaxf(v + beffv[ntl], 0.f);
            if (quad == 0) {
                const float fc = bs2f((ushort_t)sResF[p * CC + col0 + ntl * 16]);
                sRes[p * SR + col0 + ntl * 16] = f2bs(v + fc);
            }
        }
        if (p + 2 < GRP) geo_store(p + 2);
    }

    __syncthreads();

    short8 bWo[4][2];
    #pragma unroll
    for (int ks = 0; ks < 4; ++ks)
        #pragma unroll
        for (int ntl = 0; ntl < 2; ++ntl)
            bWo[ks][ntl] = *((const short8*)wsWo + ((ks * 4 + quad) * 128 + col0 + ntl * 16));

    const short* rm = sRes + m * SR;
    float4v acc2[2] = {};
    #pragma unroll
    for (int ks = 0; ks < 4; ++ks) {
        const short8 a = *(const short8*)(rm + ks * 32 + quad * 8);
        acc2[0] = MFMA(a, bWo[ks][0], acc2[0], 0, 0, 0);
        acc2[1] = MFMA(a, bWo[ks][1], acc2[1], 0, 0, 0);
    }
    const float boutv[2] = { b_out[col0], b_out[col0 + 16] };
    const float lngv[2]  = { ln_g[col0], ln_g[col0 + 16] };
    const float lnbv[2]  = { ln_b[col0], ln_b[col0 + 16] };
    #pragma unroll
    for (int r = 0; r < 4; ++r) {
        const float o0 = acc2[0][r] + boutv[0];
        const float o1 = acc2[1][r] + boutv[1];
        float ss = o0 + o1, qq2 = o0 * o0 + o1 * o1;
        #pragma unroll
        for (int d = 1; d < 16; d <<= 1) { ss += __shfl_xor(ss, d); qq2 += __shfl_xor(qq2, d); }
        if (m == 0) { sPS[wv][quad * 4 + r] = ss; sPQ[wv][quad * 4 + r] = qq2; }
    }
    __syncthreads();
    #pragma unroll
    for (int r = 0; r < 4; ++r) {
        const int R = quad * 4 + r;
        const float S = sPS[0][R] + sPS[1][R] + sPS[2][R] + sPS[3][R];
        const float Q = sPQ[0][R] + sPQ[1][R] + sPQ[2][R] + sPQ[3][R];
        const float mu  = S * (1.f / 128.f);
        const float var = fmaxf(Q * (1.f / 128.f) - mu * mu, 0.f);
        const float rstd = rsqrtf(var + LN_EPS);
        const float o0 = acc2[0][r] + boutv[0];
        const float o1 = acc2[1][r] + boutv[1];
        const size_t base = (size_t)(g0 + R) * CC;
        out[base + col0]      = fmaxf((o0 - mu) * rstd * lngv[0] + lnbv[0], 0.f);
        out[base + col0 + 16] = fmaxf((o1 - mu) * rstd * lngv[1] + lnbv[1], 0.f);
    }
}

extern "C" void kernel_launch(void* const* d_in, const int* in_sizes, int n_in,
                              void* d_out, int out_size, void* d_ws, size_t ws_size,
                              hipStream_t stream) {
    const float* points   = (const float*)d_in[0];
    const float* features = (const float*)d_in[1];
    const int*   gidx     = (const int*)  d_in[2];
    const float* w_pos    = (const float*)d_in[3];
    const float* b_pos    = (const float*)d_in[4];
    const float* w_gcm    = (const float*)d_in[5];
    const float* b_gcm    = (const float*)d_in[6];
    const float* w_out    = (const float*)d_in[7];
    const float* b_out    = (const float*)d_in[8];
    const float* ln_g     = (const float*)d_in[9];
    const float* ln_b     = (const float*)d_in[10];
    float* out = (float*)d_out;
    char* ws = (char*)d_ws;

    if (ws_size >= WS_NEED) {
        ushort_t* wsFW   = (ushort_t*)(ws + WS_FW);
        short*    wsWo   = (short*)(ws + WS_WO);
        float*    wsBeff = (float*)(ws + WS_BE);
        short*    wsWpF  = (short*)(ws + WS_WPF);
        float*    wsPG   = (float*)(ws + WS_PG);
        hipLaunchKernelGGL(prep1, dim3(13), dim3(256), 0, stream,
                           w_gcm, w_out, w_pos, b_pos, b_gcm,
                           wsWpF, wsWo, wsBeff, wsPG);
        hipLaunchKernelGGL(prep_fw, dim3(NPTS / GRP), dim3(256), 0, stream,
                           features, wsWpF, wsFW);
        hipLaunchKernelGGL(bridge_fw, dim3(NPTS / GRP), dim3(256), 0, stream,
                           points, features, gidx, wsWo, wsBeff, wsPG, wsFW,
                           b_out, ln_g, ln_b, out);
    } else {
        short* wsWp   = (short*)(ws + FB_WP);
        short* wsWo   = (short*)(ws + FB_WO);
        float* wsBeff = (float*)(ws + FB_BE);
        float* wsPG   = (float*)(ws + FB_PG);
        hipLaunchKernelGGL(prep_fold_fb, dim3(11), dim3(128), 0, stream,
                           w_pos, b_pos, w_gcm, b_gcm, wsPG, wsBeff);
        hipLaunchKernelGGL(prep_pack_fb, dim3(3), dim3(256), 0, stream,
                           w_gcm, w_out, wsPG, wsWp, wsWo);
        hipLaunchKernelGGL(bridge_fb, dim3(NPTS / GRP), dim3(256), 0, stream,
                           points, features, gidx, wsWp, wsWo, wsBeff,
                           b_out, ln_g, ln_b, out);
    }
}